// Round 12
// baseline (518.164 us; speedup 1.0000x reference)
//
#include <hip/hip_runtime.h>
#include <hip/hip_bf16.h>
#include <math.h>

#define N_NODES 50000
#define N_EDGES 800000
#define IN_DIM  128
#define HID_DIM 64

#define NBKT     196        // buckets of 256 nodes: bucket = node >> 8
#define NPASSC   200        // partition blocks, 4000 edges each
#define EDGES_PER_PASSC (N_EDGES / NPASSC)   // 4000
#define GEMM_NODES 64       // nodes per gemm block
#define NGEMM    782        // ceil(50000 / 64)
#define XS_LD    132        // xs row pad: bank stride 4, 2-way aliasing (free)

// =============== kernel 1: local-sort partition (blocks 0..199) ===============
// =============== + gemm h1b = bf16(x @ W1) (blocks 200..981) ==================
// R11-verified: PassC counting-sorts its 4000 edges into its own edge_b
// segment, writes per-(block,bucket) count/offset tables (plain stores, no
// atomics, no memset). gemm v4 register-tiled LDS GEMM (R5-verified).
__global__ __launch_bounds__(256)
void partgemm_kernel(const int* __restrict__ src, const int* __restrict__ dst,
                     const float* __restrict__ ew,
                     int* __restrict__ cnt2d, int* __restrict__ off2d,
                     int2* __restrict__ edge_b,
                     const float* __restrict__ x, const float* __restrict__ W1,
                     __hip_bfloat16* __restrict__ h1b) {
    __shared__ float w1s[IN_DIM * HID_DIM];     // 32 KB (PassC overlays counters)
    __shared__ float xs[GEMM_NODES][XS_LD];     // 33.8 KB
    int bid = blockIdx.x;
    int tid = threadIdx.x;
    if (bid < NPASSC) {
        int* cnt1   = (int*)w1s;             // [256] (196 used, rest 0 for scan)
        int* cnt2   = cnt1 + 256;            // [256]
        int* runoff = cnt2 + 256;            // [196]
        int* scuf   = runoff + 256;          // [256]
        cnt1[tid] = 0; cnt2[tid] = 0;
        __syncthreads();
        int e0 = bid * EDGES_PER_PASSC;
        for (int i = tid; i < EDGES_PER_PASSC; i += 256)
            atomicAdd(&cnt1[dst[e0 + i] >> 8], 1);
        __syncthreads();
        scuf[tid] = cnt1[tid];
        __syncthreads();
#pragma unroll
        for (int off = 1; off < 256; off <<= 1) {
            int t = (tid >= off) ? scuf[tid - off] : 0;
            __syncthreads();
            scuf[tid] += t;
            __syncthreads();
        }
        int excl = scuf[tid] - cnt1[tid];
        if (tid < NBKT) {
            runoff[tid] = excl;
            cnt2d[bid * NBKT + tid] = cnt1[tid];
            off2d[bid * NBKT + tid] = excl;
        }
        __syncthreads();
        for (int i = tid; i < EDGES_PER_PASSC; i += 256) {
            int e = e0 + i;
            int d = dst[e];
            int b = d >> 8;
            int lr = atomicAdd(&cnt2[b], 1);       // LDS atomic only
            int pos = bid * EDGES_PER_PASSC + runoff[b] + lr;
            edge_b[pos] = make_int2(src[e] | ((d & 255) << 16), __float_as_int(ew[e]));
        }
        return;
    }
    // ---- gemm path (v4, R5-verified) ----
    int gb = bid - NPASSC;
    int node0 = gb * GEMM_NODES;
    const float4* W4 = (const float4*)W1;
    float4* w1s4 = (float4*)w1s;
#pragma unroll
    for (int i = 0; i < 8; ++i) w1s4[tid + 256 * i] = W4[tid + 256 * i];
    {
        int r = tid >> 2, q = tid & 3;
        int row = node0 + r;
        if (row >= N_NODES) row = N_NODES - 1;
        const float4* xr = (const float4*)(x + (long)row * IN_DIM + q * 32);
#pragma unroll
        for (int i = 0; i < 8; ++i)
            *(float4*)&xs[r][q * 32 + i * 4] = xr[i];
    }
    __syncthreads();
    int w    = tid >> 6;
    int lane = tid & 63;
    int ng   = lane >> 2;
    int jg   = lane & 3;
    int j0   = w * 16 + jg * 4;
    float acc[4][4] = {{0.f}};
#pragma unroll 2
    for (int k = 0; k < IN_DIM; k += 4) {
        float4 wr0 = *(const float4*)&w1s[(k + 0) * HID_DIM + j0];
        float4 wr1 = *(const float4*)&w1s[(k + 1) * HID_DIM + j0];
        float4 wr2 = *(const float4*)&w1s[(k + 2) * HID_DIM + j0];
        float4 wr3 = *(const float4*)&w1s[(k + 3) * HID_DIM + j0];
#pragma unroll
        for (int i = 0; i < 4; ++i) {
            float4 xv = *(const float4*)&xs[ng + 16 * i][k];
            acc[i][0] += xv.x * wr0.x + xv.y * wr1.x + xv.z * wr2.x + xv.w * wr3.x;
            acc[i][1] += xv.x * wr0.y + xv.y * wr1.y + xv.z * wr2.y + xv.w * wr3.y;
            acc[i][2] += xv.x * wr0.z + xv.y * wr1.z + xv.z * wr2.z + xv.w * wr3.z;
            acc[i][3] += xv.x * wr0.w + xv.y * wr1.w + xv.z * wr2.w + xv.w * wr3.w;
        }
    }
#pragma unroll
    for (int i = 0; i < 4; ++i) {
        int n = node0 + ng + 16 * i;
        if (n < N_NODES) {
            __hip_bfloat16 bf[4];
            bf[0] = __float2bfloat16(acc[i][0]);
            bf[1] = __float2bfloat16(acc[i][1]);
            bf[2] = __float2bfloat16(acc[i][2]);
            bf[3] = __float2bfloat16(acc[i][3]);
            *(uint2*)&h1b[(long)n * HID_DIM + j0] = *(uint2*)bf;
        }
    }
}

// =============== kernel 2: weighted degree -> dinv (block per bucket) =========
// Reads this bucket's 200 fragments (coalesced within each), LDS-accumulates
// deg[256], writes dinv. No sort, no scatter, no edge_s.
__global__ __launch_bounds__(256)
void deg_kernel(const int* __restrict__ cnt2d, const int* __restrict__ off2d,
                const int2* __restrict__ edge_b, float* __restrict__ dinv) {
    __shared__ float degs[256];
    __shared__ int   cntS[NPASSC];
    __shared__ int   offS[NPASSC];
    int b   = blockIdx.x;
    int tid = threadIdx.x;
    int wv   = tid >> 6;
    int lane = tid & 63;
    degs[tid] = 0.0f;
    if (tid < NPASSC) {
        cntS[tid] = cnt2d[tid * NBKT + b];
        offS[tid] = off2d[tid * NBKT + b];
    }
    __syncthreads();
    for (int f = wv; f < NPASSC; f += 4) {
        int mf = cntS[f];
        long fb = (long)f * EDGES_PER_PASSC + offS[f];
        for (int j = lane; j < mf; j += 64) {
            int2 e = edge_b[fb + j];
            atomicAdd(&degs[(e.x >> 16) & 255], __int_as_float(e.y));
        }
    }
    __syncthreads();
    int node = b * 256 + tid;
    if (node < N_NODES) dinv[node] = rsqrtf(1.0f + degs[tid]);
}

// =============== kernel 3: bucket gather L1 + relu + W2 GEMV ==================
// Block per bucket, 1024 threads, 64KB LDS acc[256][64]. Per edge: all 64
// lanes load one h1b row (128B coalesced) and ds_add_f32 into acc[ldst][lane]
// (lane l -> bank l%32, 2 lanes/bank = free). Finalize 256 nodes in-block.
__global__ __launch_bounds__(1024)
void bgather1_kernel(const int* __restrict__ cnt2d, const int* __restrict__ off2d,
                     const int2* __restrict__ edge_b,
                     const __hip_bfloat16* __restrict__ h1b,
                     const float* __restrict__ dinv, const float* __restrict__ b1,
                     const float* __restrict__ W2, float* __restrict__ h2s) {
    __shared__ float acc[256][HID_DIM];      // 64 KB
    __shared__ int   cntS[NPASSC];
    __shared__ int   offS[NPASSC];
    int b    = blockIdx.x;
    int tid  = threadIdx.x;
    int wv   = tid >> 6;                     // 16 waves
    int lane = tid & 63;
    if (tid < NPASSC) {
        cntS[tid] = cnt2d[tid * NBKT + b];
        offS[tid] = off2d[tid * NBKT + b];
    }
    // zero acc: 1024 threads x 16 floats
    float4* accv = (float4*)&acc[0][0];
#pragma unroll
    for (int i = 0; i < 4; ++i) accv[tid + 1024 * i] = make_float4(0.f, 0.f, 0.f, 0.f);
    __syncthreads();
    const unsigned short* h1u = (const unsigned short*)h1b;
    for (int f = wv; f < NPASSC; f += 16) {
        int mf = cntS[f];
        long fb = (long)f * EDGES_PER_PASSC + offS[f];
        for (int j = 0; j < mf; ++j) {
            int2 e = edge_b[fb + j];                 // wave-broadcast load
            int ld = (e.x >> 16) & 255;
            int s  = e.x & 0xFFFF;
            float wdi = __int_as_float(e.y) * dinv[s];
            unsigned short us = h1u[(long)s * HID_DIM + lane];   // 128B/wave
            atomicAdd(&acc[ld][lane], wdi * __uint_as_float((unsigned)us << 16));
        }
    }
    __syncthreads();
    // finalize: wave wv handles nodes wv, wv+16, ... (16 nodes each)
    for (int ln = wv; ln < 256; ln += 16) {
        int node = b * 256 + ln;
        if (node >= N_NODES) break;
        float di = dinv[node];
        float self = __uint_as_float((unsigned)h1u[(long)node * HID_DIM + lane] << 16);
        float z = di * (acc[ln][lane] + di * self) + b1[lane];
        float h = fmaxf(z, 0.0f);
        float v = h * W2[lane];
#pragma unroll
        for (int off = 32; off > 0; off >>= 1)
            v += __shfl_down(v, off, 64);
        if (lane == 0) h2s[node] = v * di;
    }
}

// =============== kernel 4: bucket gather L2 + sigmoid =========================
// Block per bucket, 256 threads, LDS acc[256] f32. Per edge one lane does
// acc[ldst] += w * h2s[src] (random LDS-atomic collisions negligible).
__global__ __launch_bounds__(256)
void bgather2_kernel(const int* __restrict__ cnt2d, const int* __restrict__ off2d,
                     const int2* __restrict__ edge_b,
                     const float* __restrict__ h2s, const float* __restrict__ dinv,
                     const float* __restrict__ b2, float* __restrict__ out) {
    __shared__ float acc2[256];
    __shared__ int   cntS[NPASSC];
    __shared__ int   offS[NPASSC];
    int b    = blockIdx.x;
    int tid  = threadIdx.x;
    int wv   = tid >> 6;                     // 4 waves
    int lane = tid & 63;
    acc2[tid] = 0.0f;
    if (tid < NPASSC) {
        cntS[tid] = cnt2d[tid * NBKT + b];
        offS[tid] = off2d[tid * NBKT + b];
    }
    __syncthreads();
    for (int f = wv; f < NPASSC; f += 4) {
        int mf = cntS[f];
        long fb = (long)f * EDGES_PER_PASSC + offS[f];
        for (int j = lane; j < mf; j += 64) {
            int2 e = edge_b[fb + j];                 // coalesced
            atomicAdd(&acc2[(e.x >> 16) & 255],
                      __int_as_float(e.y) * h2s[e.x & 0xFFFF]);
        }
    }
    __syncthreads();
    int node = b * 256 + tid;
    if (node < N_NODES) {
        float z = dinv[node] * (acc2[tid] + h2s[node]) + b2[0];
        out[node] = 1.0f / (1.0f + expf(-z));
    }
}

extern "C" void kernel_launch(void* const* d_in, const int* in_sizes, int n_in,
                              void* d_out, int out_size, void* d_ws, size_t ws_size,
                              hipStream_t stream) {
    const float* x  = (const float*)d_in[0];
    const int*   ei = (const int*)d_in[1];
    const float* ew = (const float*)d_in[2];
    const float* W1 = (const float*)d_in[3];
    const float* b1 = (const float*)d_in[4];
    const float* W2 = (const float*)d_in[5];
    const float* b2 = (const float*)d_in[6];
    float* out = (float*)d_out;

    const int* src = ei;
    const int* dst = ei + N_EDGES;

    // workspace layout (int2 first for 8B alignment)
    char* ws = (char*)d_ws;
    int2*  edge_b  = (int2*)ws;              ws += (size_t)N_EDGES * sizeof(int2);
    int*   cnt2d   = (int*)ws;               ws += (size_t)NPASSC * NBKT * sizeof(int);
    int*   off2d   = (int*)ws;               ws += (size_t)NPASSC * NBKT * sizeof(int);
    float* dinv    = (float*)ws;             ws += N_NODES * sizeof(float);
    float* h2s     = (float*)ws;             ws += N_NODES * sizeof(float);
    // align h1b to 128 B so each 64xbf16 row sits in a single cache line
    ws = (char*)(((uintptr_t)ws + 127) & ~(uintptr_t)127);
    __hip_bfloat16* h1b = (__hip_bfloat16*)ws;  // N_NODES * HID_DIM bf16

    // 4 dispatches, no memset, no global atomics, no edge_s intermediate
    partgemm_kernel<<<NPASSC + NGEMM, 256, 0, stream>>>(src, dst, ew, cnt2d, off2d, edge_b, x, W1, h1b);
    deg_kernel<<<NBKT, 256, 0, stream>>>(cnt2d, off2d, edge_b, dinv);
    bgather1_kernel<<<NBKT, 1024, 0, stream>>>(cnt2d, off2d, edge_b, h1b, dinv, b1, W2, h2s);
    bgather2_kernel<<<NBKT, 256, 0, stream>>>(cnt2d, off2d, edge_b, h2s, dinv, b2, out);
}

// Round 13
// 432.454 us; speedup vs baseline: 1.1982x; 1.1982x over previous
//
#include <hip/hip_runtime.h>
#include <hip/hip_bf16.h>
#include <math.h>

#define N_NODES 50000
#define N_EDGES 800000
#define IN_DIM  128
#define HID_DIM 64

#define NBKT     196        // buckets of 256 nodes: bucket = node >> 8
#define BKT_CAP  5000       // mean 4092, sd 64 -> +14 sigma, safe
#define NPASSC   200        // partition blocks, 4000 edges each
#define EDGES_PER_PASSC (N_EDGES / NPASSC)   // 4000
#define GEMM_NODES 64       // nodes per gemm block
#define NGEMM    782        // ceil(50000 / 64)
#define XS_LD    132        // xs row pad: bank stride 4, 2-way aliasing (free)
#define REP      8          // PROFILING: idempotent work multiplier (divide dur by 8)

// =============== kernel 1: fused bucket-partition + gemm (R5 best, REP'd) =====
__global__ __launch_bounds__(256)
void partgemm_kernel(const int* __restrict__ src, const int* __restrict__ dst,
                     const float* __restrict__ ew, int* __restrict__ gcursor,
                     int2* __restrict__ edge_b,
                     const float* __restrict__ x, const float* __restrict__ W1,
                     __hip_bfloat16* __restrict__ h1b) {
    __shared__ float w1s[IN_DIM * HID_DIM];     // 32 KB (PassC overlays counters)
    __shared__ float xs[GEMM_NODES][XS_LD];     // 33.8 KB
    int bid = blockIdx.x;
    int tid = threadIdx.x;
    if (bid < NPASSC) {
        // ---- PassC: partition into buckets ----
        int* cnt1    = (int*)w1s;            // [196]
        int* cnt2    = cnt1 + NBKT;          // [196]
        int* runbase = cnt2 + NBKT;          // [196]
        if (tid < NBKT) cnt1[tid] = 0;
        __syncthreads();
        int e0 = bid * EDGES_PER_PASSC;
        for (int i = tid; i < EDGES_PER_PASSC; i += 256)
            atomicAdd(&cnt1[dst[e0 + i] >> 8], 1);
        __syncthreads();
        if (tid < NBKT) {                    // reservation ONCE (not idempotent)
            int c = cnt1[tid];
            runbase[tid] = (c > 0) ? atomicAdd(&gcursor[tid], c) : 0;
        }
        __syncthreads();
        for (int rep = 0; rep < REP; ++rep) {
            if (tid < NBKT) cnt2[tid] = 0;
            __syncthreads();
            for (int i = tid; i < EDGES_PER_PASSC; i += 256) {
                int e = e0 + i;
                int d = dst[e];
                int b = d >> 8;
                int lr = atomicAdd(&cnt2[b], 1);
                int pos = b * BKT_CAP + runbase[b] + lr;
                edge_b[pos] = make_int2(src[e] | ((d & 255) << 16), __float_as_int(ew[e]));
            }
            __syncthreads();
        }
        return;
    }
    // ---- gemm path (v4: register tiling) ----
    int gb = bid - NPASSC;                   // 0..781
    int node0 = gb * GEMM_NODES;
    const float4* W4 = (const float4*)W1;
    float4* w1s4 = (float4*)w1s;
#pragma unroll
    for (int i = 0; i < 8; ++i) w1s4[tid + 256 * i] = W4[tid + 256 * i];
    {
        int r = tid >> 2, q = tid & 3;
        int row = node0 + r;
        if (row >= N_NODES) row = N_NODES - 1;
        const float4* xr = (const float4*)(x + (long)row * IN_DIM + q * 32);
#pragma unroll
        for (int i = 0; i < 8; ++i)
            *(float4*)&xs[r][q * 32 + i * 4] = xr[i];
    }
    __syncthreads();
    int w    = tid >> 6;
    int lane = tid & 63;
    int ng   = lane >> 2;
    int jg   = lane & 3;
    int j0   = w * 16 + jg * 4;
    for (int rep = 0; rep < REP; ++rep) {
        float acc[4][4] = {{0.f}};
#pragma unroll 2
        for (int k = 0; k < IN_DIM; k += 4) {
            float4 wr0 = *(const float4*)&w1s[(k + 0) * HID_DIM + j0];
            float4 wr1 = *(const float4*)&w1s[(k + 1) * HID_DIM + j0];
            float4 wr2 = *(const float4*)&w1s[(k + 2) * HID_DIM + j0];
            float4 wr3 = *(const float4*)&w1s[(k + 3) * HID_DIM + j0];
#pragma unroll
            for (int i = 0; i < 4; ++i) {
                float4 xv = *(const float4*)&xs[ng + 16 * i][k];
                acc[i][0] += xv.x * wr0.x + xv.y * wr1.x + xv.z * wr2.x + xv.w * wr3.x;
                acc[i][1] += xv.x * wr0.y + xv.y * wr1.y + xv.z * wr2.y + xv.w * wr3.y;
                acc[i][2] += xv.x * wr0.z + xv.y * wr1.z + xv.z * wr2.z + xv.w * wr3.z;
                acc[i][3] += xv.x * wr0.w + xv.y * wr1.w + xv.z * wr2.w + xv.w * wr3.w;
            }
        }
#pragma unroll
        for (int i = 0; i < 4; ++i) {
            int n = node0 + ng + 16 * i;
            if (n < N_NODES) {
                __hip_bfloat16 bf[4];
                bf[0] = __float2bfloat16(acc[i][0]);
                bf[1] = __float2bfloat16(acc[i][1]);
                bf[2] = __float2bfloat16(acc[i][2]);
                bf[3] = __float2bfloat16(acc[i][3]);
                *(uint2*)&h1b[(long)n * HID_DIM + j0] = *(uint2*)bf;
            }
        }
    }
}

// =============== kernel 2: per-bucket fine sort (R5 best, REP'd) ==============
__global__ __launch_bounds__(1024)
void bsort_kernel(const int* __restrict__ gcursor, const int2* __restrict__ edge_b,
                  int2* __restrict__ edge_s, int* __restrict__ start_g,
                  int* __restrict__ cnt_g, float* __restrict__ dinv) {
    __shared__ int   cnt[256];
    __shared__ int   cnt2[256];
    __shared__ float deg[256];
    __shared__ int   sc[256];
    int b   = blockIdx.x;
    int tid = threadIdx.x;
    int M    = gcursor[b];
    int base = b * BKT_CAP;
    for (int rep = 0; rep < REP; ++rep) {
        if (tid < 256) { cnt[tid] = 0; cnt2[tid] = 0; deg[tid] = 0.0f; }
        __syncthreads();
        for (int i = tid; i < M; i += 1024) {
            int2 e = edge_b[base + i];
            int ld = (e.x >> 16) & 255;
            atomicAdd(&cnt[ld], 1);
            atomicAdd(&deg[ld], __int_as_float(e.y));
        }
        __syncthreads();
        if (tid < 256) sc[tid] = cnt[tid];
        __syncthreads();
#pragma unroll
        for (int off = 1; off < 256; off <<= 1) {
            int t = (tid >= off && tid < 256) ? sc[tid - off] : 0;
            __syncthreads();
            if (tid < 256) sc[tid] += t;
            __syncthreads();
        }
        if (tid < 256) {
            int startL = sc[tid] - cnt[tid];
            int node = b * 256 + tid;
            if (node < N_NODES) {
                start_g[node] = base + startL;
                cnt_g[node]   = cnt[tid];
                dinv[node]    = rsqrtf(1.0f + deg[tid]);
            }
            sc[tid] = startL;
        }
        __syncthreads();
        for (int i = tid; i < M; i += 1024) {
            int2 e = edge_b[base + i];
            int ld = (e.x >> 16) & 255;
            int r = atomicAdd(&cnt2[ld], 1);
            edge_s[base + sc[ld] + r] = make_int2(e.x & 0xFFFF, e.y);
        }
        __syncthreads();
    }
}

// =============== kernel 3: gather L1 + finalize + relu + W2 GEMV (REP'd) ======
__global__ void gather1_layer2_kernel(const int* __restrict__ start_g, const int* __restrict__ cnt_g,
                                      const int2* __restrict__ edge_s,
                                      const __hip_bfloat16* __restrict__ h1b,
                                      const float* __restrict__ dinv, const float* __restrict__ b1,
                                      const float* __restrict__ W2, float* __restrict__ h2s) {
    __shared__ int2 meta[4][64];
    int wave = (blockIdx.x * blockDim.x + threadIdx.x) >> 6;
    int wl = threadIdx.x >> 6;
    int lane = threadIdx.x & 63;
    if (wave >= N_NODES) return;
    int s0 = start_g[wave];
    int ctotal = cnt_g[wave];
    int c0 = (lane & 31) * 2;
    int half = lane >> 5;
    for (int rep = 0; rep < REP; ++rep) {
        float accA = 0.f, accB = 0.f, accA2 = 0.f, accB2 = 0.f;
        for (int done = 0; done < ctotal; done += 64) {
            int cnt = ctotal - done;
            if (cnt > 64) cnt = 64;
            if (lane < cnt) {
                int2 m = edge_s[s0 + done + lane];
                float w = __int_as_float(m.y) * dinv[m.x];
                meta[wl][lane] = make_int2(m.x, __float_as_int(w));
            }
            __builtin_amdgcn_wave_barrier();
            int cnte = cnt & ~1;
            int j = 0;
            for (; j + 16 <= cnte; j += 16) {
                int2 m0 = meta[wl][j +  0 + half];
                int2 m1 = meta[wl][j +  2 + half];
                int2 m2 = meta[wl][j +  4 + half];
                int2 m3 = meta[wl][j +  6 + half];
                int2 m4 = meta[wl][j +  8 + half];
                int2 m5 = meta[wl][j + 10 + half];
                int2 m6 = meta[wl][j + 12 + half];
                int2 m7 = meta[wl][j + 14 + half];
                unsigned int p0 = *(const unsigned int*)&h1b[m0.x * HID_DIM + c0];
                unsigned int p1 = *(const unsigned int*)&h1b[m1.x * HID_DIM + c0];
                unsigned int p2 = *(const unsigned int*)&h1b[m2.x * HID_DIM + c0];
                unsigned int p3 = *(const unsigned int*)&h1b[m3.x * HID_DIM + c0];
                unsigned int p4 = *(const unsigned int*)&h1b[m4.x * HID_DIM + c0];
                unsigned int p5 = *(const unsigned int*)&h1b[m5.x * HID_DIM + c0];
                unsigned int p6 = *(const unsigned int*)&h1b[m6.x * HID_DIM + c0];
                unsigned int p7 = *(const unsigned int*)&h1b[m7.x * HID_DIM + c0];
                float w0 = __int_as_float(m0.y), w1 = __int_as_float(m1.y);
                float w2 = __int_as_float(m2.y), w3 = __int_as_float(m3.y);
                float w4 = __int_as_float(m4.y), w5 = __int_as_float(m5.y);
                float w6 = __int_as_float(m6.y), w7 = __int_as_float(m7.y);
                accA  += w0 * __uint_as_float(p0 << 16);
                accB  += w0 * __uint_as_float(p0 & 0xFFFF0000u);
                accA2 += w1 * __uint_as_float(p1 << 16);
                accB2 += w1 * __uint_as_float(p1 & 0xFFFF0000u);
                accA  += w2 * __uint_as_float(p2 << 16);
                accB  += w2 * __uint_as_float(p2 & 0xFFFF0000u);
                accA2 += w3 * __uint_as_float(p3 << 16);
                accB2 += w3 * __uint_as_float(p3 & 0xFFFF0000u);
                accA  += w4 * __uint_as_float(p4 << 16);
                accB  += w4 * __uint_as_float(p4 & 0xFFFF0000u);
                accA2 += w5 * __uint_as_float(p5 << 16);
                accB2 += w5 * __uint_as_float(p5 & 0xFFFF0000u);
                accA  += w6 * __uint_as_float(p6 << 16);
                accB  += w6 * __uint_as_float(p6 & 0xFFFF0000u);
                accA2 += w7 * __uint_as_float(p7 << 16);
                accB2 += w7 * __uint_as_float(p7 & 0xFFFF0000u);
            }
            for (; j + 2 <= cnte; j += 2) {
                int2 m = meta[wl][j + half];
                unsigned int p = *(const unsigned int*)&h1b[m.x * HID_DIM + c0];
                accA += __int_as_float(m.y) * __uint_as_float(p << 16);
                accB += __int_as_float(m.y) * __uint_as_float(p & 0xFFFF0000u);
            }
            if ((cnt & 1) && half == 0) {
                int2 m = meta[wl][cnt - 1];
                unsigned int p = *(const unsigned int*)&h1b[m.x * HID_DIM + c0];
                accA += __int_as_float(m.y) * __uint_as_float(p << 16);
                accB += __int_as_float(m.y) * __uint_as_float(p & 0xFFFF0000u);
            }
            __builtin_amdgcn_wave_barrier();
        }
        accA += accA2; accB += accB2;
        accA += __shfl_xor(accA, 32, 64);
        accB += __shfl_xor(accB, 32, 64);
        float di = dinv[wave];
        unsigned int sp = *(const unsigned int*)&h1b[wave * HID_DIM + c0];
        float s0f = __uint_as_float(sp << 16);
        float s1f = __uint_as_float(sp & 0xFFFF0000u);
        float z0 = di * (accA + di * s0f) + b1[c0];
        float z1 = di * (accB + di * s1f) + b1[c0 + 1];
        float h0  = fmaxf(z0, 0.0f);
        float h1v = fmaxf(z1, 0.0f);
        float v = h0 * W2[c0] + h1v * W2[c0 + 1];
#pragma unroll
        for (int off = 16; off > 0; off >>= 1)
            v += __shfl_down(v, off, 32);
        if (lane == 0) h2s[wave] = v * di;
        __builtin_amdgcn_wave_barrier();
    }
}

// =============== kernel 4: gather L2 + sigmoid (REP'd) ========================
__global__ void gather2_final_kernel(const int* __restrict__ start_g, const int* __restrict__ cnt_g,
                                     const int2* __restrict__ edge_s,
                                     const float* __restrict__ h2s, const float* __restrict__ dinv,
                                     const float* __restrict__ b2, float* __restrict__ out) {
    int t = blockIdx.x * blockDim.x + threadIdx.x;
    int n = t >> 4;
    int sub = t & 15;
    if (n >= N_NODES) return;
    int s0 = start_g[n];
    int cnt = cnt_g[n];
    for (int rep = 0; rep < REP; ++rep) {
        float acc = 0.0f;
        for (int j = sub; j < cnt; j += 16) {
            int2 m = edge_s[s0 + j];
            acc += __int_as_float(m.y) * h2s[m.x];
        }
#pragma unroll
        for (int off = 8; off > 0; off >>= 1)
            acc += __shfl_down(acc, off, 16);
        if (sub == 0) {
            float z = dinv[n] * (acc + h2s[n]) + b2[0];
            out[n] = 1.0f / (1.0f + expf(-z));
        }
    }
}

extern "C" void kernel_launch(void* const* d_in, const int* in_sizes, int n_in,
                              void* d_out, int out_size, void* d_ws, size_t ws_size,
                              hipStream_t stream) {
    const float* x  = (const float*)d_in[0];
    const int*   ei = (const int*)d_in[1];
    const float* ew = (const float*)d_in[2];
    const float* W1 = (const float*)d_in[3];
    const float* b1 = (const float*)d_in[4];
    const float* W2 = (const float*)d_in[5];
    const float* b2 = (const float*)d_in[6];
    float* out = (float*)d_out;

    const int* src = ei;
    const int* dst = ei + N_EDGES;

    // workspace layout (int2 arrays first for 8B alignment)
    char* ws = (char*)d_ws;
    int2*  edge_b  = (int2*)ws;              ws += (size_t)NBKT * BKT_CAP * sizeof(int2);
    int2*  edge_s  = (int2*)ws;              ws += (size_t)NBKT * BKT_CAP * sizeof(int2);
    int*   gcursor = (int*)ws;               ws += NBKT * sizeof(int);
    int*   start_g = (int*)ws;               ws += N_NODES * sizeof(int);
    int*   cnt_g   = (int*)ws;               ws += N_NODES * sizeof(int);
    float* dinv    = (float*)ws;             ws += N_NODES * sizeof(float);
    float* h2s     = (float*)ws;             ws += N_NODES * sizeof(float);
    ws = (char*)(((uintptr_t)ws + 127) & ~(uintptr_t)127);
    __hip_bfloat16* h1b = (__hip_bfloat16*)ws;  // N_NODES * HID_DIM bf16

    hipMemsetAsync(gcursor, 0, NBKT * sizeof(int), stream);
    partgemm_kernel<<<NPASSC + NGEMM, 256, 0, stream>>>(src, dst, ew, gcursor, edge_b, x, W1, h1b);
    bsort_kernel<<<NBKT, 1024, 0, stream>>>(gcursor, edge_b, edge_s, start_g, cnt_g, dinv);
    gather1_layer2_kernel<<<(N_NODES * 64) / 256, 256, 0, stream>>>(start_g, cnt_g, edge_s, h1b, dinv, b1, W2, h2s);
    gather2_final_kernel<<<(N_NODES * 16 + 255) / 256, 256, 0, stream>>>(start_g, cnt_g, edge_s, h2s, dinv, b2, out);
}

// Round 14
// 161.801 us; speedup vs baseline: 3.2025x; 2.6728x over previous
//
#include <hip/hip_runtime.h>
#include <hip/hip_bf16.h>
#include <math.h>

#define N_NODES 50000
#define N_EDGES 800000
#define IN_DIM  128
#define HID_DIM 64

#define NBKT     196        // buckets of 256 nodes: bucket = node >> 8
#define BKT_CAP  5000       // per-bucket capacity: mean 4082, +14 sigma safe
#define NPASSC   800        // partition blocks, 1000 edges each (zero-atomic scheme)
#define EPB      1000       // edges per PassC block
#define GEMM_NODES 64       // nodes per gemm block
#define NGEMM    782        // ceil(50000 / 64)
#define XS_LD    132        // xs row pad: bank stride 4, 2-way aliasing (free)

// =============== kernel 1: LDS-staged partition (blocks 0..799) ===============
// =============== + gemm h1b = bf16(x @ W1) (blocks 800..1581) =================
// PassC v5: single global sweep. Stage 1000 edges in LDS (coalesced), LDS
// hist/scan, scatter from LDS into own edge_b segment. Per-(block,bucket)
// count/offset tables via plain stores (no atomics, no memset).
// gemm v4 unchanged (register-tiled LDS GEMM, R5-verified).
__global__ __launch_bounds__(256)
void partgemm_kernel(const int* __restrict__ src, const int* __restrict__ dst,
                     const float* __restrict__ ew,
                     int* __restrict__ cnt2d, int* __restrict__ off2d,
                     int2* __restrict__ edge_b,
                     const float* __restrict__ x, const float* __restrict__ W1,
                     __hip_bfloat16* __restrict__ h1b) {
    __shared__ float w1s[IN_DIM * HID_DIM];     // 32 KB (PassC overlays epack/ebkt)
    __shared__ float xs[GEMM_NODES][XS_LD];     // 33.8 KB (PassC overlays counters)
    int bid = blockIdx.x;
    int tid = threadIdx.x;
    if (bid < NPASSC) {
        int2*           epack = (int2*)w1s;                  // [1000] 8 KB
        unsigned short* ebkt  = (unsigned short*)(epack + EPB); // [1000] 2 KB
        int* cnt1   = (int*)xs;              // [256]
        int* cnt2   = cnt1 + 256;            // [256]
        int* runoff = cnt2 + 256;            // [256]
        int* scuf   = runoff + 256;          // [256]
        cnt1[tid] = 0; cnt2[tid] = 0;
        __syncthreads();
        int e0 = bid * EPB;
        // single coalesced sweep: stage + histogram
#pragma unroll
        for (int it = 0; it < 4; ++it) {
            int i = tid + 256 * it;
            if (i < EPB) {
                int e = e0 + i;
                int d = dst[e];
                epack[i] = make_int2(src[e] | ((d & 255) << 16), __float_as_int(ew[e]));
                ebkt[i]  = (unsigned short)(d >> 8);
                atomicAdd(&cnt1[d >> 8], 1);
            }
        }
        __syncthreads();
        scuf[tid] = cnt1[tid];
        __syncthreads();
#pragma unroll
        for (int off = 1; off < 256; off <<= 1) {
            int t = (tid >= off) ? scuf[tid - off] : 0;
            __syncthreads();
            scuf[tid] += t;
            __syncthreads();
        }
        int excl = scuf[tid] - cnt1[tid];
        if (tid < NBKT) {
            runoff[tid] = excl;
            cnt2d[bid * NBKT + tid] = cnt1[tid];   // plain stores
            off2d[bid * NBKT + tid] = excl;
        }
        __syncthreads();
        // scatter from LDS into own segment (bucket-sorted within segment)
#pragma unroll
        for (int it = 0; it < 4; ++it) {
            int i = tid + 256 * it;
            if (i < EPB) {
                int b = ebkt[i];
                int lr = atomicAdd(&cnt2[b], 1);   // LDS atomic only
                edge_b[bid * EPB + runoff[b] + lr] = epack[i];
            }
        }
        return;
    }
    // ---- gemm path (v4, R5-verified) ----
    int gb = bid - NPASSC;                   // 0..781
    int node0 = gb * GEMM_NODES;
    const float4* W4 = (const float4*)W1;
    float4* w1s4 = (float4*)w1s;
#pragma unroll
    for (int i = 0; i < 8; ++i) w1s4[tid + 256 * i] = W4[tid + 256 * i];
    {
        int r = tid >> 2, q = tid & 3;
        int row = node0 + r;
        if (row >= N_NODES) row = N_NODES - 1;
        const float4* xr = (const float4*)(x + (long)row * IN_DIM + q * 32);
#pragma unroll
        for (int i = 0; i < 8; ++i)
            *(float4*)&xs[r][q * 32 + i * 4] = xr[i];
    }
    __syncthreads();
    int w    = tid >> 6;
    int lane = tid & 63;
    int ng   = lane >> 2;
    int jg   = lane & 3;
    int j0   = w * 16 + jg * 4;
    float acc[4][4] = {{0.f}};
#pragma unroll 2
    for (int k = 0; k < IN_DIM; k += 4) {
        float4 wr0 = *(const float4*)&w1s[(k + 0) * HID_DIM + j0];
        float4 wr1 = *(const float4*)&w1s[(k + 1) * HID_DIM + j0];
        float4 wr2 = *(const float4*)&w1s[(k + 2) * HID_DIM + j0];
        float4 wr3 = *(const float4*)&w1s[(k + 3) * HID_DIM + j0];
#pragma unroll
        for (int i = 0; i < 4; ++i) {
            float4 xv = *(const float4*)&xs[ng + 16 * i][k];
            acc[i][0] += xv.x * wr0.x + xv.y * wr1.x + xv.z * wr2.x + xv.w * wr3.x;
            acc[i][1] += xv.x * wr0.y + xv.y * wr1.y + xv.z * wr2.y + xv.w * wr3.y;
            acc[i][2] += xv.x * wr0.z + xv.y * wr1.z + xv.z * wr2.z + xv.w * wr3.z;
            acc[i][3] += xv.x * wr0.w + xv.y * wr1.w + xv.z * wr2.w + xv.w * wr3.w;
        }
    }
#pragma unroll
    for (int i = 0; i < 4; ++i) {
        int n = node0 + ng + 16 * i;
        if (n < N_NODES) {
            __hip_bfloat16 bf[4];
            bf[0] = __float2bfloat16(acc[i][0]);
            bf[1] = __float2bfloat16(acc[i][1]);
            bf[2] = __float2bfloat16(acc[i][2]);
            bf[3] = __float2bfloat16(acc[i][3]);
            *(uint2*)&h1b[(long)n * HID_DIM + j0] = *(uint2*)bf;
        }
    }
}

// =============== kernel 2: per-bucket sort, LDS-staged (block per bucket) =====
// Stage the bucket's ~4.1K edges in LDS (per-thread-fragment copy; fragments
// contiguous), then hist/scan/scatter from LDS. One global read pass.
__global__ __launch_bounds__(1024)
void bsort_kernel(const int* __restrict__ cnt2d, const int* __restrict__ off2d,
                  const int2* __restrict__ edge_b,
                  int2* __restrict__ edge_s, int* __restrict__ start_g,
                  int* __restrict__ cnt_g, float* __restrict__ dinv) {
    __shared__ int2  ebuf[BKT_CAP];          // 40 KB
    __shared__ int   cnt[256];
    __shared__ int   cnt2[256];
    __shared__ float deg[256];
    __shared__ int   sc[256];
    __shared__ int   fs[1024];               // fragment-count scan buffer
    __shared__ int   fragbase[NPASSC + 1];
    int b   = blockIdx.x;
    int tid = threadIdx.x;
    int base = b * BKT_CAP;
    if (tid < 256) { cnt[tid] = 0; cnt2[tid] = 0; deg[tid] = 0.0f; }
    int fc = 0, foff = 0;
    if (tid < NPASSC) {
        fc   = cnt2d[tid * NBKT + b];
        foff = off2d[tid * NBKT + b];
    }
    fs[tid] = fc;                            // tid in [NPASSC,1024) -> 0
    __syncthreads();
#pragma unroll
    for (int off = 1; off < 1024; off <<= 1) {
        int t = (tid >= off) ? fs[tid - off] : 0;
        __syncthreads();
        fs[tid] += t;
        __syncthreads();
    }
    if (tid < NPASSC) fragbase[tid] = fs[tid] - fc;
    if (tid == 0) fragbase[NPASSC] = fs[1023];
    __syncthreads();
    int M = fragbase[NPASSC];
    // stage: thread tid copies its fragment (avg ~5 edges, contiguous)
    if (tid < NPASSC) {
        int fb = fragbase[tid];
        const int2* srcp = edge_b + (long)tid * EPB + foff;
        for (int j = 0; j < fc; ++j) ebuf[fb + j] = srcp[j];
    }
    __syncthreads();
    // pass 1: per-node count + weighted degree (from LDS)
    for (int i = tid; i < M; i += 1024) {
        int2 e = ebuf[i];
        int ld = (e.x >> 16) & 255;
        atomicAdd(&cnt[ld], 1);
        atomicAdd(&deg[ld], __int_as_float(e.y));
    }
    __syncthreads();
    if (tid < 256) sc[tid] = cnt[tid];
    __syncthreads();
#pragma unroll
    for (int off = 1; off < 256; off <<= 1) {
        int t = (tid >= off && tid < 256) ? sc[tid - off] : 0;
        __syncthreads();
        if (tid < 256) sc[tid] += t;
        __syncthreads();
    }
    if (tid < 256) {
        int startL = sc[tid] - cnt[tid];     // exclusive
        int node = b * 256 + tid;
        if (node < N_NODES) {
            start_g[node] = base + startL;
            cnt_g[node]   = cnt[tid];
            dinv[node]    = rsqrtf(1.0f + deg[tid]);
        }
        sc[tid] = startL;
    }
    __syncthreads();
    // pass 2: scatter node-sorted to global edge_s (from LDS)
    for (int i = tid; i < M; i += 1024) {
        int2 e = ebuf[i];
        int ld = (e.x >> 16) & 255;
        int r = atomicAdd(&cnt2[ld], 1);
        edge_s[base + sc[ld] + r] = make_int2(e.x & 0xFFFF, e.y);
    }
}

// =============== kernel 3: gather L1 + finalize + relu + W2 GEMV ==============
// R5-verified body, unchanged.
__global__ void gather1_layer2_kernel(const int* __restrict__ start_g, const int* __restrict__ cnt_g,
                                      const int2* __restrict__ edge_s,
                                      const __hip_bfloat16* __restrict__ h1b,
                                      const float* __restrict__ dinv, const float* __restrict__ b1,
                                      const float* __restrict__ W2, float* __restrict__ h2s) {
    __shared__ int2 meta[4][64];
    int wave = (blockIdx.x * blockDim.x + threadIdx.x) >> 6;
    int wl = threadIdx.x >> 6;
    int lane = threadIdx.x & 63;
    if (wave >= N_NODES) return;
    int s0 = start_g[wave];
    int ctotal = cnt_g[wave];
    int c0 = (lane & 31) * 2;
    int half = lane >> 5;
    float accA = 0.f, accB = 0.f, accA2 = 0.f, accB2 = 0.f;
    for (int done = 0; done < ctotal; done += 64) {
        int cnt = ctotal - done;
        if (cnt > 64) cnt = 64;
        if (lane < cnt) {
            int2 m = edge_s[s0 + done + lane];
            float w = __int_as_float(m.y) * dinv[m.x];
            meta[wl][lane] = make_int2(m.x, __float_as_int(w));
        }
        __builtin_amdgcn_wave_barrier();
        int cnte = cnt & ~1;
        int j = 0;
        for (; j + 16 <= cnte; j += 16) {
            int2 m0 = meta[wl][j +  0 + half];
            int2 m1 = meta[wl][j +  2 + half];
            int2 m2 = meta[wl][j +  4 + half];
            int2 m3 = meta[wl][j +  6 + half];
            int2 m4 = meta[wl][j +  8 + half];
            int2 m5 = meta[wl][j + 10 + half];
            int2 m6 = meta[wl][j + 12 + half];
            int2 m7 = meta[wl][j + 14 + half];
            unsigned int p0 = *(const unsigned int*)&h1b[m0.x * HID_DIM + c0];
            unsigned int p1 = *(const unsigned int*)&h1b[m1.x * HID_DIM + c0];
            unsigned int p2 = *(const unsigned int*)&h1b[m2.x * HID_DIM + c0];
            unsigned int p3 = *(const unsigned int*)&h1b[m3.x * HID_DIM + c0];
            unsigned int p4 = *(const unsigned int*)&h1b[m4.x * HID_DIM + c0];
            unsigned int p5 = *(const unsigned int*)&h1b[m5.x * HID_DIM + c0];
            unsigned int p6 = *(const unsigned int*)&h1b[m6.x * HID_DIM + c0];
            unsigned int p7 = *(const unsigned int*)&h1b[m7.x * HID_DIM + c0];
            float w0 = __int_as_float(m0.y), w1 = __int_as_float(m1.y);
            float w2 = __int_as_float(m2.y), w3 = __int_as_float(m3.y);
            float w4 = __int_as_float(m4.y), w5 = __int_as_float(m5.y);
            float w6 = __int_as_float(m6.y), w7 = __int_as_float(m7.y);
            accA  += w0 * __uint_as_float(p0 << 16);
            accB  += w0 * __uint_as_float(p0 & 0xFFFF0000u);
            accA2 += w1 * __uint_as_float(p1 << 16);
            accB2 += w1 * __uint_as_float(p1 & 0xFFFF0000u);
            accA  += w2 * __uint_as_float(p2 << 16);
            accB  += w2 * __uint_as_float(p2 & 0xFFFF0000u);
            accA2 += w3 * __uint_as_float(p3 << 16);
            accB2 += w3 * __uint_as_float(p3 & 0xFFFF0000u);
            accA  += w4 * __uint_as_float(p4 << 16);
            accB  += w4 * __uint_as_float(p4 & 0xFFFF0000u);
            accA2 += w5 * __uint_as_float(p5 << 16);
            accB2 += w5 * __uint_as_float(p5 & 0xFFFF0000u);
            accA  += w6 * __uint_as_float(p6 << 16);
            accB  += w6 * __uint_as_float(p6 & 0xFFFF0000u);
            accA2 += w7 * __uint_as_float(p7 << 16);
            accB2 += w7 * __uint_as_float(p7 & 0xFFFF0000u);
        }
        for (; j + 2 <= cnte; j += 2) {
            int2 m = meta[wl][j + half];
            unsigned int p = *(const unsigned int*)&h1b[m.x * HID_DIM + c0];
            accA += __int_as_float(m.y) * __uint_as_float(p << 16);
            accB += __int_as_float(m.y) * __uint_as_float(p & 0xFFFF0000u);
        }
        if ((cnt & 1) && half == 0) {
            int2 m = meta[wl][cnt - 1];
            unsigned int p = *(const unsigned int*)&h1b[m.x * HID_DIM + c0];
            accA += __int_as_float(m.y) * __uint_as_float(p << 16);
            accB += __int_as_float(m.y) * __uint_as_float(p & 0xFFFF0000u);
        }
        __builtin_amdgcn_wave_barrier();
    }
    accA += accA2; accB += accB2;
    accA += __shfl_xor(accA, 32, 64);
    accB += __shfl_xor(accB, 32, 64);
    float di = dinv[wave];
    unsigned int sp = *(const unsigned int*)&h1b[wave * HID_DIM + c0];
    float s0f = __uint_as_float(sp << 16);
    float s1f = __uint_as_float(sp & 0xFFFF0000u);
    float z0 = di * (accA + di * s0f) + b1[c0];
    float z1 = di * (accB + di * s1f) + b1[c0 + 1];
    float h0  = fmaxf(z0, 0.0f);
    float h1v = fmaxf(z1, 0.0f);
    float v = h0 * W2[c0] + h1v * W2[c0 + 1];
#pragma unroll
    for (int off = 16; off > 0; off >>= 1)
        v += __shfl_down(v, off, 32);
    if (lane == 0) h2s[wave] = v * di;
}

// =============== kernel 4: gather L2 + sigmoid ================================
__global__ void gather2_final_kernel(const int* __restrict__ start_g, const int* __restrict__ cnt_g,
                                     const int2* __restrict__ edge_s,
                                     const float* __restrict__ h2s, const float* __restrict__ dinv,
                                     const float* __restrict__ b2, float* __restrict__ out) {
    int t = blockIdx.x * blockDim.x + threadIdx.x;
    int n = t >> 4;
    int sub = t & 15;
    if (n >= N_NODES) return;
    int s0 = start_g[n];
    int cnt = cnt_g[n];
    float acc = 0.0f;
    for (int j = sub; j < cnt; j += 16) {
        int2 m = edge_s[s0 + j];
        acc += __int_as_float(m.y) * h2s[m.x];   // dinv[src] already folded
    }
#pragma unroll
    for (int off = 8; off > 0; off >>= 1)
        acc += __shfl_down(acc, off, 16);
    if (sub == 0) {
        float z = dinv[n] * (acc + h2s[n]) + b2[0];
        out[n] = 1.0f / (1.0f + expf(-z));
    }
}

extern "C" void kernel_launch(void* const* d_in, const int* in_sizes, int n_in,
                              void* d_out, int out_size, void* d_ws, size_t ws_size,
                              hipStream_t stream) {
    const float* x  = (const float*)d_in[0];
    const int*   ei = (const int*)d_in[1];
    const float* ew = (const float*)d_in[2];
    const float* W1 = (const float*)d_in[3];
    const float* b1 = (const float*)d_in[4];
    const float* W2 = (const float*)d_in[5];
    const float* b2 = (const float*)d_in[6];
    float* out = (float*)d_out;

    const int* src = ei;
    const int* dst = ei + N_EDGES;

    // workspace layout (int2 first for 8B alignment)
    char* ws = (char*)d_ws;
    int2*  edge_b  = (int2*)ws;              ws += (size_t)NPASSC * EPB * sizeof(int2);
    int2*  edge_s  = (int2*)ws;              ws += (size_t)NBKT * BKT_CAP * sizeof(int2);
    int*   cnt2d   = (int*)ws;               ws += (size_t)NPASSC * NBKT * sizeof(int);
    int*   off2d   = (int*)ws;               ws += (size_t)NPASSC * NBKT * sizeof(int);
    int*   start_g = (int*)ws;               ws += N_NODES * sizeof(int);
    int*   cnt_g   = (int*)ws;               ws += N_NODES * sizeof(int);
    float* dinv    = (float*)ws;             ws += N_NODES * sizeof(float);
    float* h2s     = (float*)ws;             ws += N_NODES * sizeof(float);
    ws = (char*)(((uintptr_t)ws + 127) & ~(uintptr_t)127);
    __hip_bfloat16* h1b = (__hip_bfloat16*)ws;  // N_NODES * HID_DIM bf16

    // 4 dispatches, no memset, no global atomics
    partgemm_kernel<<<NPASSC + NGEMM, 256, 0, stream>>>(src, dst, ew, cnt2d, off2d, edge_b, x, W1, h1b);
    bsort_kernel<<<NBKT, 1024, 0, stream>>>(cnt2d, off2d, edge_b, edge_s, start_g, cnt_g, dinv);
    gather1_layer2_kernel<<<(N_NODES * 64) / 256, 256, 0, stream>>>(start_g, cnt_g, edge_s, h1b, dinv, b1, W2, h2s);
    gather2_final_kernel<<<(N_NODES * 16 + 255) / 256, 256, 0, stream>>>(start_g, cnt_g, edge_s, h2s, dinv, b2, out);
}

// Round 15
// 152.621 us; speedup vs baseline: 3.3951x; 1.0601x over previous
//
#include <hip/hip_runtime.h>
#include <hip/hip_bf16.h>
#include <math.h>

#define N_NODES 50000
#define N_EDGES 800000
#define IN_DIM  128
#define HID_DIM 64

#define NBKT     196        // buckets of 256 nodes: bucket = node >> 8
#define BKT_CAP  5000       // mean 4092, sd 64 -> +14 sigma, safe
#define NPASSC   200        // partition blocks, 4000 edges each (R5 verified)
#define EDGES_PER_PASSC (N_EDGES / NPASSC)   // 4000
#define GEMM_NODES 64       // nodes per gemm block
#define NGEMM    782        // ceil(50000 / 64)
#define XS_LD    132        // xs row pad: bank stride 4, 2-way aliasing (free)

// =============== kernel 1: fused bucket-partition (blocks 0..199) =============
// =============== + gemm h1b = bf16(x @ W1) (blocks 200..981) ==================
// PassC v6: R5 design (LDS hist -> gcursor reservation -> bucket-contiguous
// edge_b) but ONE vectorized global sweep (int4/float4, 4 edges/lane/load)
// staging into LDS; scatter pass reads LDS only. gemm v4 unchanged.
__global__ __launch_bounds__(256)
void partgemm_kernel(const int* __restrict__ src, const int* __restrict__ dst,
                     const float* __restrict__ ew, int* __restrict__ gcursor,
                     int2* __restrict__ edge_b,
                     const float* __restrict__ x, const float* __restrict__ W1,
                     __hip_bfloat16* __restrict__ h1b) {
    __shared__ float w1s[IN_DIM * HID_DIM];     // 32 KB (PassC: epack overlay)
    __shared__ float xs[GEMM_NODES][XS_LD];     // 33.8 KB (PassC: ebkt+counters)
    int bid = blockIdx.x;
    int tid = threadIdx.x;
    if (bid < NPASSC) {
        int2*           epack = (int2*)w1s;                      // [4000] 32 KB
        unsigned short* ebkt  = (unsigned short*)&xs[0][0];      // [4000] 8 KB
        int* cnt1    = (int*)(ebkt + EDGES_PER_PASSC);           // [256]
        int* cnt2    = cnt1 + 256;                               // [256]
        int* runbase = cnt2 + 256;                               // [196]
        cnt1[tid] = 0; cnt2[tid] = 0;
        __syncthreads();
        int e0 = bid * EDGES_PER_PASSC;
        // single vectorized sweep: stage + histogram (1000 int4-quads total)
        const int4*   s4p = (const int4*)(src + e0);
        const int4*   d4p = (const int4*)(dst + e0);
        const float4* w4p = (const float4*)(ew + e0);
#pragma unroll
        for (int it = 0; it < 4; ++it) {
            int q = tid + 256 * it;              // quad index 0..999
            if (q < EDGES_PER_PASSC / 4) {
                int4   s4 = s4p[q];
                int4   d4 = d4p[q];
                float4 w4 = w4p[q];
                int i = q * 4;
                epack[i + 0] = make_int2(s4.x | ((d4.x & 255) << 16), __float_as_int(w4.x));
                epack[i + 1] = make_int2(s4.y | ((d4.y & 255) << 16), __float_as_int(w4.y));
                epack[i + 2] = make_int2(s4.z | ((d4.z & 255) << 16), __float_as_int(w4.z));
                epack[i + 3] = make_int2(s4.w | ((d4.w & 255) << 16), __float_as_int(w4.w));
                ebkt[i + 0] = (unsigned short)(d4.x >> 8);
                ebkt[i + 1] = (unsigned short)(d4.y >> 8);
                ebkt[i + 2] = (unsigned short)(d4.z >> 8);
                ebkt[i + 3] = (unsigned short)(d4.w >> 8);
                atomicAdd(&cnt1[d4.x >> 8], 1);
                atomicAdd(&cnt1[d4.y >> 8], 1);
                atomicAdd(&cnt1[d4.z >> 8], 1);
                atomicAdd(&cnt1[d4.w >> 8], 1);
            }
        }
        __syncthreads();
        if (tid < NBKT) {
            int c = cnt1[tid];
            runbase[tid] = (c > 0) ? atomicAdd(&gcursor[tid], c) : 0;
        }
        __syncthreads();
        // scatter from LDS into bucket-contiguous edge_b (no global re-reads)
        for (int i = tid; i < EDGES_PER_PASSC; i += 256) {
            int b = ebkt[i];
            int lr = atomicAdd(&cnt2[b], 1);     // LDS atomic only
            edge_b[b * BKT_CAP + runbase[b] + lr] = epack[i];
        }
        return;
    }
    // ---- gemm path (v4: register tiling, R5-verified) ----
    int gb = bid - NPASSC;                   // 0..781
    int node0 = gb * GEMM_NODES;
    const float4* W4 = (const float4*)W1;
    float4* w1s4 = (float4*)w1s;
#pragma unroll
    for (int i = 0; i < 8; ++i) w1s4[tid + 256 * i] = W4[tid + 256 * i];
    {
        int r = tid >> 2, q = tid & 3;
        int row = node0 + r;
        if (row >= N_NODES) row = N_NODES - 1;
        const float4* xr = (const float4*)(x + (long)row * IN_DIM + q * 32);
#pragma unroll
        for (int i = 0; i < 8; ++i)
            *(float4*)&xs[r][q * 32 + i * 4] = xr[i];
    }
    __syncthreads();
    int w    = tid >> 6;
    int lane = tid & 63;
    int ng   = lane >> 2;
    int jg   = lane & 3;
    int j0   = w * 16 + jg * 4;
    float acc[4][4] = {{0.f}};
#pragma unroll 2
    for (int k = 0; k < IN_DIM; k += 4) {
        float4 wr0 = *(const float4*)&w1s[(k + 0) * HID_DIM + j0];
        float4 wr1 = *(const float4*)&w1s[(k + 1) * HID_DIM + j0];
        float4 wr2 = *(const float4*)&w1s[(k + 2) * HID_DIM + j0];
        float4 wr3 = *(const float4*)&w1s[(k + 3) * HID_DIM + j0];
#pragma unroll
        for (int i = 0; i < 4; ++i) {
            float4 xv = *(const float4*)&xs[ng + 16 * i][k];
            acc[i][0] += xv.x * wr0.x + xv.y * wr1.x + xv.z * wr2.x + xv.w * wr3.x;
            acc[i][1] += xv.x * wr0.y + xv.y * wr1.y + xv.z * wr2.y + xv.w * wr3.y;
            acc[i][2] += xv.x * wr0.z + xv.y * wr1.z + xv.z * wr2.z + xv.w * wr3.z;
            acc[i][3] += xv.x * wr0.w + xv.y * wr1.w + xv.z * wr2.w + xv.w * wr3.w;
        }
    }
#pragma unroll
    for (int i = 0; i < 4; ++i) {
        int n = node0 + ng + 16 * i;
        if (n < N_NODES) {
            __hip_bfloat16 bf[4];
            bf[0] = __float2bfloat16(acc[i][0]);
            bf[1] = __float2bfloat16(acc[i][1]);
            bf[2] = __float2bfloat16(acc[i][2]);
            bf[3] = __float2bfloat16(acc[i][3]);
            *(uint2*)&h1b[(long)n * HID_DIM + j0] = *(uint2*)bf;
        }
    }
}

// =============== kernel 2: per-bucket fine sort + start/cnt/dinv ==============
// R5-verified body, unchanged (bucket-contiguous edge_b read, 1024 threads).
__global__ __launch_bounds__(1024)
void bsort_kernel(const int* __restrict__ gcursor, const int2* __restrict__ edge_b,
                  int2* __restrict__ edge_s, int* __restrict__ start_g,
                  int* __restrict__ cnt_g, float* __restrict__ dinv) {
    __shared__ int   cnt[256];
    __shared__ int   cnt2[256];
    __shared__ float deg[256];
    __shared__ int   sc[256];
    int b   = blockIdx.x;
    int tid = threadIdx.x;
    int M    = gcursor[b];
    int base = b * BKT_CAP;
    if (tid < 256) { cnt[tid] = 0; cnt2[tid] = 0; deg[tid] = 0.0f; }
    __syncthreads();
    for (int i = tid; i < M; i += 1024) {
        int2 e = edge_b[base + i];
        int ld = (e.x >> 16) & 255;
        atomicAdd(&cnt[ld], 1);
        atomicAdd(&deg[ld], __int_as_float(e.y));
    }
    __syncthreads();
    if (tid < 256) sc[tid] = cnt[tid];
    __syncthreads();
#pragma unroll
    for (int off = 1; off < 256; off <<= 1) {
        int t = (tid >= off && tid < 256) ? sc[tid - off] : 0;
        __syncthreads();
        if (tid < 256) sc[tid] += t;
        __syncthreads();
    }
    if (tid < 256) {
        int startL = sc[tid] - cnt[tid];     // exclusive
        int node = b * 256 + tid;
        if (node < N_NODES) {
            start_g[node] = base + startL;
            cnt_g[node]   = cnt[tid];
            dinv[node]    = rsqrtf(1.0f + deg[tid]);
        }
        sc[tid] = startL;
    }
    __syncthreads();
    for (int i = tid; i < M; i += 1024) {
        int2 e = edge_b[base + i];
        int ld = (e.x >> 16) & 255;
        int r = atomicAdd(&cnt2[ld], 1);
        edge_s[base + sc[ld] + r] = make_int2(e.x & 0xFFFF, e.y);
    }
}

// =============== kernel 3: gather L1 + finalize + relu + W2 GEMV ==============
// R5-verified body, unchanged.
__global__ void gather1_layer2_kernel(const int* __restrict__ start_g, const int* __restrict__ cnt_g,
                                      const int2* __restrict__ edge_s,
                                      const __hip_bfloat16* __restrict__ h1b,
                                      const float* __restrict__ dinv, const float* __restrict__ b1,
                                      const float* __restrict__ W2, float* __restrict__ h2s) {
    __shared__ int2 meta[4][64];
    int wave = (blockIdx.x * blockDim.x + threadIdx.x) >> 6;
    int wl = threadIdx.x >> 6;
    int lane = threadIdx.x & 63;
    if (wave >= N_NODES) return;
    int s0 = start_g[wave];
    int ctotal = cnt_g[wave];
    int c0 = (lane & 31) * 2;
    int half = lane >> 5;
    float accA = 0.f, accB = 0.f, accA2 = 0.f, accB2 = 0.f;
    for (int done = 0; done < ctotal; done += 64) {
        int cnt = ctotal - done;
        if (cnt > 64) cnt = 64;
        if (lane < cnt) {
            int2 m = edge_s[s0 + done + lane];
            float w = __int_as_float(m.y) * dinv[m.x];
            meta[wl][lane] = make_int2(m.x, __float_as_int(w));
        }
        __builtin_amdgcn_wave_barrier();
        int cnte = cnt & ~1;
        int j = 0;
        for (; j + 16 <= cnte; j += 16) {
            int2 m0 = meta[wl][j +  0 + half];
            int2 m1 = meta[wl][j +  2 + half];
            int2 m2 = meta[wl][j +  4 + half];
            int2 m3 = meta[wl][j +  6 + half];
            int2 m4 = meta[wl][j +  8 + half];
            int2 m5 = meta[wl][j + 10 + half];
            int2 m6 = meta[wl][j + 12 + half];
            int2 m7 = meta[wl][j + 14 + half];
            unsigned int p0 = *(const unsigned int*)&h1b[m0.x * HID_DIM + c0];
            unsigned int p1 = *(const unsigned int*)&h1b[m1.x * HID_DIM + c0];
            unsigned int p2 = *(const unsigned int*)&h1b[m2.x * HID_DIM + c0];
            unsigned int p3 = *(const unsigned int*)&h1b[m3.x * HID_DIM + c0];
            unsigned int p4 = *(const unsigned int*)&h1b[m4.x * HID_DIM + c0];
            unsigned int p5 = *(const unsigned int*)&h1b[m5.x * HID_DIM + c0];
            unsigned int p6 = *(const unsigned int*)&h1b[m6.x * HID_DIM + c0];
            unsigned int p7 = *(const unsigned int*)&h1b[m7.x * HID_DIM + c0];
            float w0 = __int_as_float(m0.y), w1 = __int_as_float(m1.y);
            float w2 = __int_as_float(m2.y), w3 = __int_as_float(m3.y);
            float w4 = __int_as_float(m4.y), w5 = __int_as_float(m5.y);
            float w6 = __int_as_float(m6.y), w7 = __int_as_float(m7.y);
            accA  += w0 * __uint_as_float(p0 << 16);
            accB  += w0 * __uint_as_float(p0 & 0xFFFF0000u);
            accA2 += w1 * __uint_as_float(p1 << 16);
            accB2 += w1 * __uint_as_float(p1 & 0xFFFF0000u);
            accA  += w2 * __uint_as_float(p2 << 16);
            accB  += w2 * __uint_as_float(p2 & 0xFFFF0000u);
            accA2 += w3 * __uint_as_float(p3 << 16);
            accB2 += w3 * __uint_as_float(p3 & 0xFFFF0000u);
            accA  += w4 * __uint_as_float(p4 << 16);
            accB  += w4 * __uint_as_float(p4 & 0xFFFF0000u);
            accA2 += w5 * __uint_as_float(p5 << 16);
            accB2 += w5 * __uint_as_float(p5 & 0xFFFF0000u);
            accA  += w6 * __uint_as_float(p6 << 16);
            accB  += w6 * __uint_as_float(p6 & 0xFFFF0000u);
            accA2 += w7 * __uint_as_float(p7 << 16);
            accB2 += w7 * __uint_as_float(p7 & 0xFFFF0000u);
        }
        for (; j + 2 <= cnte; j += 2) {
            int2 m = meta[wl][j + half];
            unsigned int p = *(const unsigned int*)&h1b[m.x * HID_DIM + c0];
            accA += __int_as_float(m.y) * __uint_as_float(p << 16);
            accB += __int_as_float(m.y) * __uint_as_float(p & 0xFFFF0000u);
        }
        if ((cnt & 1) && half == 0) {
            int2 m = meta[wl][cnt - 1];
            unsigned int p = *(const unsigned int*)&h1b[m.x * HID_DIM + c0];
            accA += __int_as_float(m.y) * __uint_as_float(p << 16);
            accB += __int_as_float(m.y) * __uint_as_float(p & 0xFFFF0000u);
        }
        __builtin_amdgcn_wave_barrier();
    }
    accA += accA2; accB += accB2;
    accA += __shfl_xor(accA, 32, 64);
    accB += __shfl_xor(accB, 32, 64);
    float di = dinv[wave];
    unsigned int sp = *(const unsigned int*)&h1b[wave * HID_DIM + c0];
    float s0f = __uint_as_float(sp << 16);
    float s1f = __uint_as_float(sp & 0xFFFF0000u);
    float z0 = di * (accA + di * s0f) + b1[c0];
    float z1 = di * (accB + di * s1f) + b1[c0 + 1];
    float h0  = fmaxf(z0, 0.0f);
    float h1v = fmaxf(z1, 0.0f);
    float v = h0 * W2[c0] + h1v * W2[c0 + 1];
#pragma unroll
    for (int off = 16; off > 0; off >>= 1)
        v += __shfl_down(v, off, 32);
    if (lane == 0) h2s[wave] = v * di;
}

// =============== kernel 4: gather L2 + sigmoid ================================
// R5-verified body, unchanged.
__global__ void gather2_final_kernel(const int* __restrict__ start_g, const int* __restrict__ cnt_g,
                                     const int2* __restrict__ edge_s,
                                     const float* __restrict__ h2s, const float* __restrict__ dinv,
                                     const float* __restrict__ b2, float* __restrict__ out) {
    int t = blockIdx.x * blockDim.x + threadIdx.x;
    int n = t >> 4;
    int sub = t & 15;
    if (n >= N_NODES) return;
    int s0 = start_g[n];
    int cnt = cnt_g[n];
    float acc = 0.0f;
    for (int j = sub; j < cnt; j += 16) {
        int2 m = edge_s[s0 + j];
        acc += __int_as_float(m.y) * h2s[m.x];   // dinv[src] already folded
    }
#pragma unroll
    for (int off = 8; off > 0; off >>= 1)
        acc += __shfl_down(acc, off, 16);
    if (sub == 0) {
        float z = dinv[n] * (acc + h2s[n]) + b2[0];
        out[n] = 1.0f / (1.0f + expf(-z));
    }
}

extern "C" void kernel_launch(void* const* d_in, const int* in_sizes, int n_in,
                              void* d_out, int out_size, void* d_ws, size_t ws_size,
                              hipStream_t stream) {
    const float* x  = (const float*)d_in[0];
    const int*   ei = (const int*)d_in[1];
    const float* ew = (const float*)d_in[2];
    const float* W1 = (const float*)d_in[3];
    const float* b1 = (const float*)d_in[4];
    const float* W2 = (const float*)d_in[5];
    const float* b2 = (const float*)d_in[6];
    float* out = (float*)d_out;

    const int* src = ei;
    const int* dst = ei + N_EDGES;

    // workspace layout (int2 arrays first for 8B alignment) — R5 layout
    char* ws = (char*)d_ws;
    int2*  edge_b  = (int2*)ws;              ws += (size_t)NBKT * BKT_CAP * sizeof(int2);
    int2*  edge_s  = (int2*)ws;              ws += (size_t)NBKT * BKT_CAP * sizeof(int2);
    int*   gcursor = (int*)ws;               ws += NBKT * sizeof(int);
    int*   start_g = (int*)ws;               ws += N_NODES * sizeof(int);
    int*   cnt_g   = (int*)ws;               ws += N_NODES * sizeof(int);
    float* dinv    = (float*)ws;             ws += N_NODES * sizeof(float);
    float* h2s     = (float*)ws;             ws += N_NODES * sizeof(float);
    ws = (char*)(((uintptr_t)ws + 127) & ~(uintptr_t)127);
    __hip_bfloat16* h1b = (__hip_bfloat16*)ws;  // N_NODES * HID_DIM bf16

    hipMemsetAsync(gcursor, 0, NBKT * sizeof(int), stream);
    partgemm_kernel<<<NPASSC + NGEMM, 256, 0, stream>>>(src, dst, ew, gcursor, edge_b, x, W1, h1b);
    bsort_kernel<<<NBKT, 1024, 0, stream>>>(gcursor, edge_b, edge_s, start_g, cnt_g, dinv);
    gather1_layer2_kernel<<<(N_NODES * 64) / 256, 256, 0, stream>>>(start_g, cnt_g, edge_s, h1b, dinv, b1, W2, h2s);
    gather2_final_kernel<<<(N_NODES * 16 + 255) / 256, 256, 0, stream>>>(start_g, cnt_g, edge_s, h2s, dinv, b2, out);
}

// Round 16
// 151.396 us; speedup vs baseline: 3.4226x; 1.0081x over previous
//
#include <hip/hip_runtime.h>
#include <hip/hip_bf16.h>
#include <math.h>

#define N_NODES 50000
#define N_EDGES 800000
#define IN_DIM  128
#define HID_DIM 64

#define NBKT     196        // buckets of 256 nodes: bucket = node >> 8
#define BKT_CAP  5000       // mean 4092, sd 64 -> +14 sigma, safe
#define NPASSC   200        // partition blocks, 4000 edges each (R5 verified)
#define EDGES_PER_PASSC (N_EDGES / NPASSC)   // 4000
#define GEMM_NODES 64       // nodes per gemm block
#define NGEMM    782        // ceil(50000 / 64)
#define XS_LD    132        // xs row pad: bank stride 4, 2-way aliasing (free)

// =============== kernel 1: fused bucket-partition (blocks 0..199) =============
// =============== + gemm h1b = bf16(x @ W1) (blocks 200..981) ==================
// PassC v7: R15's single vectorized sweep + SORTED scatter. pos2orig LDS
// permutation makes consecutive threads write consecutive edge_b addresses
// within each bucket run (~16x fewer store transactions). gemm v4 unchanged.
__global__ __launch_bounds__(256)
void partgemm_kernel(const int* __restrict__ src, const int* __restrict__ dst,
                     const float* __restrict__ ew, int* __restrict__ gcursor,
                     int2* __restrict__ edge_b,
                     const float* __restrict__ x, const float* __restrict__ W1,
                     __hip_bfloat16* __restrict__ h1b) {
    __shared__ float w1s[IN_DIM * HID_DIM];     // 32 KB (PassC: epack overlay)
    __shared__ float xs[GEMM_NODES][XS_LD];     // 33.8 KB (PassC: ebkt+perm+cnt)
    int bid = blockIdx.x;
    int tid = threadIdx.x;
    if (bid < NPASSC) {
        int2*           epack    = (int2*)w1s;                   // [4000] 32 KB
        unsigned short* ebkt     = (unsigned short*)&xs[0][0];   // [4000] 8 KB
        unsigned short* pos2orig = ebkt + EDGES_PER_PASSC;       // [4000] 8 KB
        int* cnt1    = (int*)(pos2orig + EDGES_PER_PASSC);       // [256]
        int* cnt2    = cnt1 + 256;                               // [256]
        int* runbase = cnt2 + 256;                               // [196]
        cnt1[tid] = 0; cnt2[tid] = 0;
        __syncthreads();
        int e0 = bid * EDGES_PER_PASSC;
        // single vectorized sweep: stage + histogram (1000 int4-quads total)
        const int4*   s4p = (const int4*)(src + e0);
        const int4*   d4p = (const int4*)(dst + e0);
        const float4* w4p = (const float4*)(ew + e0);
#pragma unroll
        for (int it = 0; it < 4; ++it) {
            int q = tid + 256 * it;              // quad index 0..999
            if (q < EDGES_PER_PASSC / 4) {
                int4   s4 = s4p[q];
                int4   d4 = d4p[q];
                float4 w4 = w4p[q];
                int i = q * 4;
                epack[i + 0] = make_int2(s4.x | ((d4.x & 255) << 16), __float_as_int(w4.x));
                epack[i + 1] = make_int2(s4.y | ((d4.y & 255) << 16), __float_as_int(w4.y));
                epack[i + 2] = make_int2(s4.z | ((d4.z & 255) << 16), __float_as_int(w4.z));
                epack[i + 3] = make_int2(s4.w | ((d4.w & 255) << 16), __float_as_int(w4.w));
                ebkt[i + 0] = (unsigned short)(d4.x >> 8);
                ebkt[i + 1] = (unsigned short)(d4.y >> 8);
                ebkt[i + 2] = (unsigned short)(d4.z >> 8);
                ebkt[i + 3] = (unsigned short)(d4.w >> 8);
                atomicAdd(&cnt1[d4.x >> 8], 1);
                atomicAdd(&cnt1[d4.y >> 8], 1);
                atomicAdd(&cnt1[d4.z >> 8], 1);
                atomicAdd(&cnt1[d4.w >> 8], 1);
            }
        }
        __syncthreads();
        // exclusive scan of cnt1 over 256 buckets -> runoff (reuse cnt1 slot)
        // (scan in shared: use pos2orig's tail? keep separate small buffer)
        __shared__ int scuf[256];
        scuf[tid] = cnt1[tid];
        __syncthreads();
#pragma unroll
        for (int off = 1; off < 256; off <<= 1) {
            int t = (tid >= off) ? scuf[tid - off] : 0;
            __syncthreads();
            scuf[tid] += t;
            __syncthreads();
        }
        int runoff_t = scuf[tid] - cnt1[tid];    // exclusive prefix (local)
        if (tid < NBKT) {
            int c = cnt1[tid];
            runbase[tid] = (c > 0) ? atomicAdd(&gcursor[tid], c) : 0;
        }
        // stash runoff in cnt1 (histogram no longer needed)
        __syncthreads();
        cnt1[tid] = runoff_t;
        __syncthreads();
        // pass A: build bucket-sorted permutation (LDS only)
        for (int i = tid; i < EDGES_PER_PASSC; i += 256) {
            int b = ebkt[i];
            int lr = atomicAdd(&cnt2[b], 1);     // LDS atomic only
            pos2orig[cnt1[b] + lr] = (unsigned short)i;
        }
        __syncthreads();
        // pass B: coalesced scatter — consecutive i -> consecutive addresses
        for (int i = tid; i < EDGES_PER_PASSC; i += 256) {
            int orig = pos2orig[i];
            int2 e = epack[orig];
            int b = ebkt[orig];
            edge_b[b * BKT_CAP + runbase[b] + (i - cnt1[b])] = e;
        }
        return;
    }
    // ---- gemm path (v4: register tiling, R5-verified) ----
    int gb = bid - NPASSC;                   // 0..781
    int node0 = gb * GEMM_NODES;
    const float4* W4 = (const float4*)W1;
    float4* w1s4 = (float4*)w1s;
#pragma unroll
    for (int i = 0; i < 8; ++i) w1s4[tid + 256 * i] = W4[tid + 256 * i];
    {
        int r = tid >> 2, q = tid & 3;
        int row = node0 + r;
        if (row >= N_NODES) row = N_NODES - 1;
        const float4* xr = (const float4*)(x + (long)row * IN_DIM + q * 32);
#pragma unroll
        for (int i = 0; i < 8; ++i)
            *(float4*)&xs[r][q * 32 + i * 4] = xr[i];
    }
    __syncthreads();
    int w    = tid >> 6;
    int lane = tid & 63;
    int ng   = lane >> 2;
    int jg   = lane & 3;
    int j0   = w * 16 + jg * 4;
    float acc[4][4] = {{0.f}};
#pragma unroll 2
    for (int k = 0; k < IN_DIM; k += 4) {
        float4 wr0 = *(const float4*)&w1s[(k + 0) * HID_DIM + j0];
        float4 wr1 = *(const float4*)&w1s[(k + 1) * HID_DIM + j0];
        float4 wr2 = *(const float4*)&w1s[(k + 2) * HID_DIM + j0];
        float4 wr3 = *(const float4*)&w1s[(k + 3) * HID_DIM + j0];
#pragma unroll
        for (int i = 0; i < 4; ++i) {
            float4 xv = *(const float4*)&xs[ng + 16 * i][k];
            acc[i][0] += xv.x * wr0.x + xv.y * wr1.x + xv.z * wr2.x + xv.w * wr3.x;
            acc[i][1] += xv.x * wr0.y + xv.y * wr1.y + xv.z * wr2.y + xv.w * wr3.y;
            acc[i][2] += xv.x * wr0.z + xv.y * wr1.z + xv.z * wr2.z + xv.w * wr3.z;
            acc[i][3] += xv.x * wr0.w + xv.y * wr1.w + xv.z * wr2.w + xv.w * wr3.w;
        }
    }
#pragma unroll
    for (int i = 0; i < 4; ++i) {
        int n = node0 + ng + 16 * i;
        if (n < N_NODES) {
            __hip_bfloat16 bf[4];
            bf[0] = __float2bfloat16(acc[i][0]);
            bf[1] = __float2bfloat16(acc[i][1]);
            bf[2] = __float2bfloat16(acc[i][2]);
            bf[3] = __float2bfloat16(acc[i][3]);
            *(uint2*)&h1b[(long)n * HID_DIM + j0] = *(uint2*)bf;
        }
    }
}

// =============== kernel 2: per-bucket fine sort + start/cnt/dinv ==============
// R5-verified body; reads vectorized as int4 (2 edges/load).
__global__ __launch_bounds__(1024)
void bsort_kernel(const int* __restrict__ gcursor, const int2* __restrict__ edge_b,
                  int2* __restrict__ edge_s, int* __restrict__ start_g,
                  int* __restrict__ cnt_g, float* __restrict__ dinv) {
    __shared__ int   cnt[256];
    __shared__ int   cnt2[256];
    __shared__ float deg[256];
    __shared__ int   sc[256];
    int b   = blockIdx.x;
    int tid = threadIdx.x;
    int M    = gcursor[b];
    int base = b * BKT_CAP;
    if (tid < 256) { cnt[tid] = 0; cnt2[tid] = 0; deg[tid] = 0.0f; }
    __syncthreads();
    // pass 1: count + weighted degree (int4 = 2 edges per load)
    const int4* eb4 = (const int4*)(edge_b + base);
    int Mh = M >> 1;
    for (int i = tid; i < Mh; i += 1024) {
        int4 p = eb4[i];
        int ld0 = (p.x >> 16) & 255;
        int ld1 = (p.z >> 16) & 255;
        atomicAdd(&cnt[ld0], 1);
        atomicAdd(&deg[ld0], __int_as_float(p.y));
        atomicAdd(&cnt[ld1], 1);
        atomicAdd(&deg[ld1], __int_as_float(p.w));
    }
    if (tid == 0 && (M & 1)) {
        int2 e = edge_b[base + M - 1];
        int ld = (e.x >> 16) & 255;
        atomicAdd(&cnt[ld], 1);
        atomicAdd(&deg[ld], __int_as_float(e.y));
    }
    __syncthreads();
    if (tid < 256) sc[tid] = cnt[tid];
    __syncthreads();
#pragma unroll
    for (int off = 1; off < 256; off <<= 1) {
        int t = (tid >= off && tid < 256) ? sc[tid - off] : 0;
        __syncthreads();
        if (tid < 256) sc[tid] += t;
        __syncthreads();
    }
    if (tid < 256) {
        int startL = sc[tid] - cnt[tid];     // exclusive
        int node = b * 256 + tid;
        if (node < N_NODES) {
            start_g[node] = base + startL;
            cnt_g[node]   = cnt[tid];
            dinv[node]    = rsqrtf(1.0f + deg[tid]);
        }
        sc[tid] = startL;
    }
    __syncthreads();
    // pass 2: scatter node-sorted (int4 = 2 edges per load)
    for (int i = tid; i < Mh; i += 1024) {
        int4 p = eb4[i];
        int ld0 = (p.x >> 16) & 255;
        int r0 = atomicAdd(&cnt2[ld0], 1);
        edge_s[base + sc[ld0] + r0] = make_int2(p.x & 0xFFFF, p.y);
        int ld1 = (p.z >> 16) & 255;
        int r1 = atomicAdd(&cnt2[ld1], 1);
        edge_s[base + sc[ld1] + r1] = make_int2(p.z & 0xFFFF, p.w);
    }
    if (tid == 0 && (M & 1)) {
        int2 e = edge_b[base + M - 1];
        int ld = (e.x >> 16) & 255;
        int r = atomicAdd(&cnt2[ld], 1);
        edge_s[base + sc[ld] + r] = make_int2(e.x & 0xFFFF, e.y);
    }
}

// =============== kernel 3: gather L1 + finalize + relu + W2 GEMV ==============
// R5-verified body, unchanged.
__global__ void gather1_layer2_kernel(const int* __restrict__ start_g, const int* __restrict__ cnt_g,
                                      const int2* __restrict__ edge_s,
                                      const __hip_bfloat16* __restrict__ h1b,
                                      const float* __restrict__ dinv, const float* __restrict__ b1,
                                      const float* __restrict__ W2, float* __restrict__ h2s) {
    __shared__ int2 meta[4][64];
    int wave = (blockIdx.x * blockDim.x + threadIdx.x) >> 6;
    int wl = threadIdx.x >> 6;
    int lane = threadIdx.x & 63;
    if (wave >= N_NODES) return;
    int s0 = start_g[wave];
    int ctotal = cnt_g[wave];
    int c0 = (lane & 31) * 2;
    int half = lane >> 5;
    float accA = 0.f, accB = 0.f, accA2 = 0.f, accB2 = 0.f;
    for (int done = 0; done < ctotal; done += 64) {
        int cnt = ctotal - done;
        if (cnt > 64) cnt = 64;
        if (lane < cnt) {
            int2 m = edge_s[s0 + done + lane];
            float w = __int_as_float(m.y) * dinv[m.x];
            meta[wl][lane] = make_int2(m.x, __float_as_int(w));
        }
        __builtin_amdgcn_wave_barrier();
        int cnte = cnt & ~1;
        int j = 0;
        for (; j + 16 <= cnte; j += 16) {
            int2 m0 = meta[wl][j +  0 + half];
            int2 m1 = meta[wl][j +  2 + half];
            int2 m2 = meta[wl][j +  4 + half];
            int2 m3 = meta[wl][j +  6 + half];
            int2 m4 = meta[wl][j +  8 + half];
            int2 m5 = meta[wl][j + 10 + half];
            int2 m6 = meta[wl][j + 12 + half];
            int2 m7 = meta[wl][j + 14 + half];
            unsigned int p0 = *(const unsigned int*)&h1b[m0.x * HID_DIM + c0];
            unsigned int p1 = *(const unsigned int*)&h1b[m1.x * HID_DIM + c0];
            unsigned int p2 = *(const unsigned int*)&h1b[m2.x * HID_DIM + c0];
            unsigned int p3 = *(const unsigned int*)&h1b[m3.x * HID_DIM + c0];
            unsigned int p4 = *(const unsigned int*)&h1b[m4.x * HID_DIM + c0];
            unsigned int p5 = *(const unsigned int*)&h1b[m5.x * HID_DIM + c0];
            unsigned int p6 = *(const unsigned int*)&h1b[m6.x * HID_DIM + c0];
            unsigned int p7 = *(const unsigned int*)&h1b[m7.x * HID_DIM + c0];
            float w0 = __int_as_float(m0.y), w1 = __int_as_float(m1.y);
            float w2 = __int_as_float(m2.y), w3 = __int_as_float(m3.y);
            float w4 = __int_as_float(m4.y), w5 = __int_as_float(m5.y);
            float w6 = __int_as_float(m6.y), w7 = __int_as_float(m7.y);
            accA  += w0 * __uint_as_float(p0 << 16);
            accB  += w0 * __uint_as_float(p0 & 0xFFFF0000u);
            accA2 += w1 * __uint_as_float(p1 << 16);
            accB2 += w1 * __uint_as_float(p1 & 0xFFFF0000u);
            accA  += w2 * __uint_as_float(p2 << 16);
            accB  += w2 * __uint_as_float(p2 & 0xFFFF0000u);
            accA2 += w3 * __uint_as_float(p3 << 16);
            accB2 += w3 * __uint_as_float(p3 & 0xFFFF0000u);
            accA  += w4 * __uint_as_float(p4 << 16);
            accB  += w4 * __uint_as_float(p4 & 0xFFFF0000u);
            accA2 += w5 * __uint_as_float(p5 << 16);
            accB2 += w5 * __uint_as_float(p5 & 0xFFFF0000u);
            accA  += w6 * __uint_as_float(p6 << 16);
            accB  += w6 * __uint_as_float(p6 & 0xFFFF0000u);
            accA2 += w7 * __uint_as_float(p7 << 16);
            accB2 += w7 * __uint_as_float(p7 & 0xFFFF0000u);
        }
        for (; j + 2 <= cnte; j += 2) {
            int2 m = meta[wl][j + half];
            unsigned int p = *(const unsigned int*)&h1b[m.x * HID_DIM + c0];
            accA += __int_as_float(m.y) * __uint_as_float(p << 16);
            accB += __int_as_float(m.y) * __uint_as_float(p & 0xFFFF0000u);
        }
        if ((cnt & 1) && half == 0) {
            int2 m = meta[wl][cnt - 1];
            unsigned int p = *(const unsigned int*)&h1b[m.x * HID_DIM + c0];
            accA += __int_as_float(m.y) * __uint_as_float(p << 16);
            accB += __int_as_float(m.y) * __uint_as_float(p & 0xFFFF0000u);
        }
        __builtin_amdgcn_wave_barrier();
    }
    accA += accA2; accB += accB2;
    accA += __shfl_xor(accA, 32, 64);
    accB += __shfl_xor(accB, 32, 64);
    float di = dinv[wave];
    unsigned int sp = *(const unsigned int*)&h1b[wave * HID_DIM + c0];
    float s0f = __uint_as_float(sp << 16);
    float s1f = __uint_as_float(sp & 0xFFFF0000u);
    float z0 = di * (accA + di * s0f) + b1[c0];
    float z1 = di * (accB + di * s1f) + b1[c0 + 1];
    float h0  = fmaxf(z0, 0.0f);
    float h1v = fmaxf(z1, 0.0f);
    float v = h0 * W2[c0] + h1v * W2[c0 + 1];
#pragma unroll
    for (int off = 16; off > 0; off >>= 1)
        v += __shfl_down(v, off, 32);
    if (lane == 0) h2s[wave] = v * di;
}

// =============== kernel 4: gather L2 + sigmoid ================================
// R5-verified body, unchanged.
__global__ void gather2_final_kernel(const int* __restrict__ start_g, const int* __restrict__ cnt_g,
                                     const int2* __restrict__ edge_s,
                                     const float* __restrict__ h2s, const float* __restrict__ dinv,
                                     const float* __restrict__ b2, float* __restrict__ out) {
    int t = blockIdx.x * blockDim.x + threadIdx.x;
    int n = t >> 4;
    int sub = t & 15;
    if (n >= N_NODES) return;
    int s0 = start_g[n];
    int cnt = cnt_g[n];
    float acc = 0.0f;
    for (int j = sub; j < cnt; j += 16) {
        int2 m = edge_s[s0 + j];
        acc += __int_as_float(m.y) * h2s[m.x];   // dinv[src] already folded
    }
#pragma unroll
    for (int off = 8; off > 0; off >>= 1)
        acc += __shfl_down(acc, off, 16);
    if (sub == 0) {
        float z = dinv[n] * (acc + h2s[n]) + b2[0];
        out[n] = 1.0f / (1.0f + expf(-z));
    }
}

extern "C" void kernel_launch(void* const* d_in, const int* in_sizes, int n_in,
                              void* d_out, int out_size, void* d_ws, size_t ws_size,
                              hipStream_t stream) {
    const float* x  = (const float*)d_in[0];
    const int*   ei = (const int*)d_in[1];
    const float* ew = (const float*)d_in[2];
    const float* W1 = (const float*)d_in[3];
    const float* b1 = (const float*)d_in[4];
    const float* W2 = (const float*)d_in[5];
    const float* b2 = (const float*)d_in[6];
    float* out = (float*)d_out;

    const int* src = ei;
    const int* dst = ei + N_EDGES;

    // workspace layout (int2 arrays first for 8B alignment) — R5 layout
    char* ws = (char*)d_ws;
    int2*  edge_b  = (int2*)ws;              ws += (size_t)NBKT * BKT_CAP * sizeof(int2);
    int2*  edge_s  = (int2*)ws;              ws += (size_t)NBKT * BKT_CAP * sizeof(int2);
    int*   gcursor = (int*)ws;               ws += NBKT * sizeof(int);
    int*   start_g = (int*)ws;               ws += N_NODES * sizeof(int);
    int*   cnt_g   = (int*)ws;               ws += N_NODES * sizeof(int);
    float* dinv    = (float*)ws;             ws += N_NODES * sizeof(float);
    float* h2s     = (float*)ws;             ws += N_NODES * sizeof(float);
    ws = (char*)(((uintptr_t)ws + 127) & ~(uintptr_t)127);
    __hip_bfloat16* h1b = (__hip_bfloat16*)ws;  // N_NODES * HID_DIM bf16

    hipMemsetAsync(gcursor, 0, NBKT * sizeof(int), stream);
    partgemm_kernel<<<NPASSC + NGEMM, 256, 0, stream>>>(src, dst, ew, gcursor, edge_b, x, W1, h1b);
    bsort_kernel<<<NBKT, 1024, 0, stream>>>(gcursor, edge_b, edge_s, start_g, cnt_g, dinv);
    gather1_layer2_kernel<<<(N_NODES * 64) / 256, 256, 0, stream>>>(start_g, cnt_g, edge_s, h1b, dinv, b1, W2, h2s);
    gather2_final_kernel<<<(N_NODES * 16 + 255) / 256, 256, 0, stream>>>(start_g, cnt_g, edge_s, h2s, dinv, b2, out);
}

// Round 17
// 151.100 us; speedup vs baseline: 3.4293x; 1.0020x over previous
//
#include <hip/hip_runtime.h>
#include <hip/hip_bf16.h>
#include <math.h>

#define N_NODES 50000
#define N_EDGES 800000
#define IN_DIM  128
#define HID_DIM 64

#define NBKT     196        // buckets of 256 nodes: bucket = node >> 8
#define BKT_CAP  5000       // mean 4092, sd 64 -> +14 sigma, safe
#define NPASSC   200        // partition blocks, 4000 edges each (R5 verified)
#define EDGES_PER_PASSC (N_EDGES / NPASSC)   // 4000
#define GEMM_NODES 64       // nodes per gemm block
#define NGEMM    782        // ceil(50000 / 64)
#define XS_LD    132        // xs row pad: bank stride 4, 2-way aliasing (free)
#define GC_STRIDE 16        // gcursor: one counter per 64B line (kills cross-XCD line bouncing)

// =============== kernel 1: fused bucket-partition (blocks 0..199) =============
// =============== + gemm h1b = bf16(x @ W1) (blocks 200..981) ==================
// PassC v8 = R16 v7 (single vectorized sweep + sorted scatter) with gcursor
// padded to 64B/counter. 39K reservation atomics now hit 196 independent
// lines instead of 13 contended ones. gemm v4 unchanged.
__global__ __launch_bounds__(256)
void partgemm_kernel(const int* __restrict__ src, const int* __restrict__ dst,
                     const float* __restrict__ ew, int* __restrict__ gcursor,
                     int2* __restrict__ edge_b,
                     const float* __restrict__ x, const float* __restrict__ W1,
                     __hip_bfloat16* __restrict__ h1b) {
    __shared__ float w1s[IN_DIM * HID_DIM];     // 32 KB (PassC: epack overlay)
    __shared__ float xs[GEMM_NODES][XS_LD];     // 33.8 KB (PassC: ebkt+perm+cnt)
    int bid = blockIdx.x;
    int tid = threadIdx.x;
    if (bid < NPASSC) {
        int2*           epack    = (int2*)w1s;                   // [4000] 32 KB
        unsigned short* ebkt     = (unsigned short*)&xs[0][0];   // [4000] 8 KB
        unsigned short* pos2orig = ebkt + EDGES_PER_PASSC;       // [4000] 8 KB
        int* cnt1    = (int*)(pos2orig + EDGES_PER_PASSC);       // [256]
        int* cnt2    = cnt1 + 256;                               // [256]
        int* runbase = cnt2 + 256;                               // [196]
        cnt1[tid] = 0; cnt2[tid] = 0;
        __syncthreads();
        int e0 = bid * EDGES_PER_PASSC;
        // single vectorized sweep: stage + histogram (1000 int4-quads total)
        const int4*   s4p = (const int4*)(src + e0);
        const int4*   d4p = (const int4*)(dst + e0);
        const float4* w4p = (const float4*)(ew + e0);
#pragma unroll
        for (int it = 0; it < 4; ++it) {
            int q = tid + 256 * it;              // quad index 0..999
            if (q < EDGES_PER_PASSC / 4) {
                int4   s4 = s4p[q];
                int4   d4 = d4p[q];
                float4 w4 = w4p[q];
                int i = q * 4;
                epack[i + 0] = make_int2(s4.x | ((d4.x & 255) << 16), __float_as_int(w4.x));
                epack[i + 1] = make_int2(s4.y | ((d4.y & 255) << 16), __float_as_int(w4.y));
                epack[i + 2] = make_int2(s4.z | ((d4.z & 255) << 16), __float_as_int(w4.z));
                epack[i + 3] = make_int2(s4.w | ((d4.w & 255) << 16), __float_as_int(w4.w));
                ebkt[i + 0] = (unsigned short)(d4.x >> 8);
                ebkt[i + 1] = (unsigned short)(d4.y >> 8);
                ebkt[i + 2] = (unsigned short)(d4.z >> 8);
                ebkt[i + 3] = (unsigned short)(d4.w >> 8);
                atomicAdd(&cnt1[d4.x >> 8], 1);
                atomicAdd(&cnt1[d4.y >> 8], 1);
                atomicAdd(&cnt1[d4.z >> 8], 1);
                atomicAdd(&cnt1[d4.w >> 8], 1);
            }
        }
        __syncthreads();
        // exclusive scan of cnt1 over 256 buckets
        __shared__ int scuf[256];
        scuf[tid] = cnt1[tid];
        __syncthreads();
#pragma unroll
        for (int off = 1; off < 256; off <<= 1) {
            int t = (tid >= off) ? scuf[tid - off] : 0;
            __syncthreads();
            scuf[tid] += t;
            __syncthreads();
        }
        int runoff_t = scuf[tid] - cnt1[tid];    // exclusive prefix (local)
        if (tid < NBKT) {
            int c = cnt1[tid];
            runbase[tid] = (c > 0) ? atomicAdd(&gcursor[tid * GC_STRIDE], c) : 0;
        }
        // stash runoff in cnt1 (histogram no longer needed)
        __syncthreads();
        cnt1[tid] = runoff_t;
        __syncthreads();
        // pass A: build bucket-sorted permutation (LDS only)
        for (int i = tid; i < EDGES_PER_PASSC; i += 256) {
            int b = ebkt[i];
            int lr = atomicAdd(&cnt2[b], 1);     // LDS atomic only
            pos2orig[cnt1[b] + lr] = (unsigned short)i;
        }
        __syncthreads();
        // pass B: coalesced scatter — consecutive i -> consecutive addresses
        for (int i = tid; i < EDGES_PER_PASSC; i += 256) {
            int orig = pos2orig[i];
            int2 e = epack[orig];
            int b = ebkt[orig];
            edge_b[b * BKT_CAP + runbase[b] + (i - cnt1[b])] = e;
        }
        return;
    }
    // ---- gemm path (v4: register tiling, R5-verified) ----
    int gb = bid - NPASSC;                   // 0..781
    int node0 = gb * GEMM_NODES;
    const float4* W4 = (const float4*)W1;
    float4* w1s4 = (float4*)w1s;
#pragma unroll
    for (int i = 0; i < 8; ++i) w1s4[tid + 256 * i] = W4[tid + 256 * i];
    {
        int r = tid >> 2, q = tid & 3;
        int row = node0 + r;
        if (row >= N_NODES) row = N_NODES - 1;
        const float4* xr = (const float4*)(x + (long)row * IN_DIM + q * 32);
#pragma unroll
        for (int i = 0; i < 8; ++i)
            *(float4*)&xs[r][q * 32 + i * 4] = xr[i];
    }
    __syncthreads();
    int w    = tid >> 6;
    int lane = tid & 63;
    int ng   = lane >> 2;
    int jg   = lane & 3;
    int j0   = w * 16 + jg * 4;
    float acc[4][4] = {{0.f}};
#pragma unroll 2
    for (int k = 0; k < IN_DIM; k += 4) {
        float4 wr0 = *(const float4*)&w1s[(k + 0) * HID_DIM + j0];
        float4 wr1 = *(const float4*)&w1s[(k + 1) * HID_DIM + j0];
        float4 wr2 = *(const float4*)&w1s[(k + 2) * HID_DIM + j0];
        float4 wr3 = *(const float4*)&w1s[(k + 3) * HID_DIM + j0];
#pragma unroll
        for (int i = 0; i < 4; ++i) {
            float4 xv = *(const float4*)&xs[ng + 16 * i][k];
            acc[i][0] += xv.x * wr0.x + xv.y * wr1.x + xv.z * wr2.x + xv.w * wr3.x;
            acc[i][1] += xv.x * wr0.y + xv.y * wr1.y + xv.z * wr2.y + xv.w * wr3.y;
            acc[i][2] += xv.x * wr0.z + xv.y * wr1.z + xv.z * wr2.z + xv.w * wr3.z;
            acc[i][3] += xv.x * wr0.w + xv.y * wr1.w + xv.z * wr2.w + xv.w * wr3.w;
        }
    }
#pragma unroll
    for (int i = 0; i < 4; ++i) {
        int n = node0 + ng + 16 * i;
        if (n < N_NODES) {
            __hip_bfloat16 bf[4];
            bf[0] = __float2bfloat16(acc[i][0]);
            bf[1] = __float2bfloat16(acc[i][1]);
            bf[2] = __float2bfloat16(acc[i][2]);
            bf[3] = __float2bfloat16(acc[i][3]);
            *(uint2*)&h1b[(long)n * HID_DIM + j0] = *(uint2*)bf;
        }
    }
}

// =============== kernel 2: per-bucket fine sort + start/cnt/dinv ==============
// R16 body (int4 reads), gcursor access strided.
__global__ __launch_bounds__(1024)
void bsort_kernel(const int* __restrict__ gcursor, const int2* __restrict__ edge_b,
                  int2* __restrict__ edge_s, int* __restrict__ start_g,
                  int* __restrict__ cnt_g, float* __restrict__ dinv) {
    __shared__ int   cnt[256];
    __shared__ int   cnt2[256];
    __shared__ float deg[256];
    __shared__ int   sc[256];
    int b   = blockIdx.x;
    int tid = threadIdx.x;
    int M    = gcursor[b * GC_STRIDE];
    int base = b * BKT_CAP;
    if (tid < 256) { cnt[tid] = 0; cnt2[tid] = 0; deg[tid] = 0.0f; }
    __syncthreads();
    // pass 1: count + weighted degree (int4 = 2 edges per load)
    const int4* eb4 = (const int4*)(edge_b + base);
    int Mh = M >> 1;
    for (int i = tid; i < Mh; i += 1024) {
        int4 p = eb4[i];
        int ld0 = (p.x >> 16) & 255;
        int ld1 = (p.z >> 16) & 255;
        atomicAdd(&cnt[ld0], 1);
        atomicAdd(&deg[ld0], __int_as_float(p.y));
        atomicAdd(&cnt[ld1], 1);
        atomicAdd(&deg[ld1], __int_as_float(p.w));
    }
    if (tid == 0 && (M & 1)) {
        int2 e = edge_b[base + M - 1];
        int ld = (e.x >> 16) & 255;
        atomicAdd(&cnt[ld], 1);
        atomicAdd(&deg[ld], __int_as_float(e.y));
    }
    __syncthreads();
    if (tid < 256) sc[tid] = cnt[tid];
    __syncthreads();
#pragma unroll
    for (int off = 1; off < 256; off <<= 1) {
        int t = (tid >= off && tid < 256) ? sc[tid - off] : 0;
        __syncthreads();
        if (tid < 256) sc[tid] += t;
        __syncthreads();
    }
    if (tid < 256) {
        int startL = sc[tid] - cnt[tid];     // exclusive
        int node = b * 256 + tid;
        if (node < N_NODES) {
            start_g[node] = base + startL;
            cnt_g[node]   = cnt[tid];
            dinv[node]    = rsqrtf(1.0f + deg[tid]);
        }
        sc[tid] = startL;
    }
    __syncthreads();
    // pass 2: scatter node-sorted (int4 = 2 edges per load)
    for (int i = tid; i < Mh; i += 1024) {
        int4 p = eb4[i];
        int ld0 = (p.x >> 16) & 255;
        int r0 = atomicAdd(&cnt2[ld0], 1);
        edge_s[base + sc[ld0] + r0] = make_int2(p.x & 0xFFFF, p.y);
        int ld1 = (p.z >> 16) & 255;
        int r1 = atomicAdd(&cnt2[ld1], 1);
        edge_s[base + sc[ld1] + r1] = make_int2(p.z & 0xFFFF, p.w);
    }
    if (tid == 0 && (M & 1)) {
        int2 e = edge_b[base + M - 1];
        int ld = (e.x >> 16) & 255;
        int r = atomicAdd(&cnt2[ld], 1);
        edge_s[base + sc[ld] + r] = make_int2(e.x & 0xFFFF, e.y);
    }
}

// =============== kernel 3: gather L1 + finalize + relu + W2 GEMV ==============
// R5-verified body, unchanged.
__global__ void gather1_layer2_kernel(const int* __restrict__ start_g, const int* __restrict__ cnt_g,
                                      const int2* __restrict__ edge_s,
                                      const __hip_bfloat16* __restrict__ h1b,
                                      const float* __restrict__ dinv, const float* __restrict__ b1,
                                      const float* __restrict__ W2, float* __restrict__ h2s) {
    __shared__ int2 meta[4][64];
    int wave = (blockIdx.x * blockDim.x + threadIdx.x) >> 6;
    int wl = threadIdx.x >> 6;
    int lane = threadIdx.x & 63;
    if (wave >= N_NODES) return;
    int s0 = start_g[wave];
    int ctotal = cnt_g[wave];
    int c0 = (lane & 31) * 2;
    int half = lane >> 5;
    float accA = 0.f, accB = 0.f, accA2 = 0.f, accB2 = 0.f;
    for (int done = 0; done < ctotal; done += 64) {
        int cnt = ctotal - done;
        if (cnt > 64) cnt = 64;
        if (lane < cnt) {
            int2 m = edge_s[s0 + done + lane];
            float w = __int_as_float(m.y) * dinv[m.x];
            meta[wl][lane] = make_int2(m.x, __float_as_int(w));
        }
        __builtin_amdgcn_wave_barrier();
        int cnte = cnt & ~1;
        int j = 0;
        for (; j + 16 <= cnte; j += 16) {
            int2 m0 = meta[wl][j +  0 + half];
            int2 m1 = meta[wl][j +  2 + half];
            int2 m2 = meta[wl][j +  4 + half];
            int2 m3 = meta[wl][j +  6 + half];
            int2 m4 = meta[wl][j +  8 + half];
            int2 m5 = meta[wl][j + 10 + half];
            int2 m6 = meta[wl][j + 12 + half];
            int2 m7 = meta[wl][j + 14 + half];
            unsigned int p0 = *(const unsigned int*)&h1b[m0.x * HID_DIM + c0];
            unsigned int p1 = *(const unsigned int*)&h1b[m1.x * HID_DIM + c0];
            unsigned int p2 = *(const unsigned int*)&h1b[m2.x * HID_DIM + c0];
            unsigned int p3 = *(const unsigned int*)&h1b[m3.x * HID_DIM + c0];
            unsigned int p4 = *(const unsigned int*)&h1b[m4.x * HID_DIM + c0];
            unsigned int p5 = *(const unsigned int*)&h1b[m5.x * HID_DIM + c0];
            unsigned int p6 = *(const unsigned int*)&h1b[m6.x * HID_DIM + c0];
            unsigned int p7 = *(const unsigned int*)&h1b[m7.x * HID_DIM + c0];
            float w0 = __int_as_float(m0.y), w1 = __int_as_float(m1.y);
            float w2 = __int_as_float(m2.y), w3 = __int_as_float(m3.y);
            float w4 = __int_as_float(m4.y), w5 = __int_as_float(m5.y);
            float w6 = __int_as_float(m6.y), w7 = __int_as_float(m7.y);
            accA  += w0 * __uint_as_float(p0 << 16);
            accB  += w0 * __uint_as_float(p0 & 0xFFFF0000u);
            accA2 += w1 * __uint_as_float(p1 << 16);
            accB2 += w1 * __uint_as_float(p1 & 0xFFFF0000u);
            accA  += w2 * __uint_as_float(p2 << 16);
            accB  += w2 * __uint_as_float(p2 & 0xFFFF0000u);
            accA2 += w3 * __uint_as_float(p3 << 16);
            accB2 += w3 * __uint_as_float(p3 & 0xFFFF0000u);
            accA  += w4 * __uint_as_float(p4 << 16);
            accB  += w4 * __uint_as_float(p4 & 0xFFFF0000u);
            accA2 += w5 * __uint_as_float(p5 << 16);
            accB2 += w5 * __uint_as_float(p5 & 0xFFFF0000u);
            accA  += w6 * __uint_as_float(p6 << 16);
            accB  += w6 * __uint_as_float(p6 & 0xFFFF0000u);
            accA2 += w7 * __uint_as_float(p7 << 16);
            accB2 += w7 * __uint_as_float(p7 & 0xFFFF0000u);
        }
        for (; j + 2 <= cnte; j += 2) {
            int2 m = meta[wl][j + half];
            unsigned int p = *(const unsigned int*)&h1b[m.x * HID_DIM + c0];
            accA += __int_as_float(m.y) * __uint_as_float(p << 16);
            accB += __int_as_float(m.y) * __uint_as_float(p & 0xFFFF0000u);
        }
        if ((cnt & 1) && half == 0) {
            int2 m = meta[wl][cnt - 1];
            unsigned int p = *(const unsigned int*)&h1b[m.x * HID_DIM + c0];
            accA += __int_as_float(m.y) * __uint_as_float(p << 16);
            accB += __int_as_float(m.y) * __uint_as_float(p & 0xFFFF0000u);
        }
        __builtin_amdgcn_wave_barrier();
    }
    accA += accA2; accB += accB2;
    accA += __shfl_xor(accA, 32, 64);
    accB += __shfl_xor(accB, 32, 64);
    float di = dinv[wave];
    unsigned int sp = *(const unsigned int*)&h1b[wave * HID_DIM + c0];
    float s0f = __uint_as_float(sp << 16);
    float s1f = __uint_as_float(sp & 0xFFFF0000u);
    float z0 = di * (accA + di * s0f) + b1[c0];
    float z1 = di * (accB + di * s1f) + b1[c0 + 1];
    float h0  = fmaxf(z0, 0.0f);
    float h1v = fmaxf(z1, 0.0f);
    float v = h0 * W2[c0] + h1v * W2[c0 + 1];
#pragma unroll
    for (int off = 16; off > 0; off >>= 1)
        v += __shfl_down(v, off, 32);
    if (lane == 0) h2s[wave] = v * di;
}

// =============== kernel 4: gather L2 + sigmoid ================================
// R5-verified body, unchanged.
__global__ void gather2_final_kernel(const int* __restrict__ start_g, const int* __restrict__ cnt_g,
                                     const int2* __restrict__ edge_s,
                                     const float* __restrict__ h2s, const float* __restrict__ dinv,
                                     const float* __restrict__ b2, float* __restrict__ out) {
    int t = blockIdx.x * blockDim.x + threadIdx.x;
    int n = t >> 4;
    int sub = t & 15;
    if (n >= N_NODES) return;
    int s0 = start_g[n];
    int cnt = cnt_g[n];
    float acc = 0.0f;
    for (int j = sub; j < cnt; j += 16) {
        int2 m = edge_s[s0 + j];
        acc += __int_as_float(m.y) * h2s[m.x];   // dinv[src] already folded
    }
#pragma unroll
    for (int off = 8; off > 0; off >>= 1)
        acc += __shfl_down(acc, off, 16);
    if (sub == 0) {
        float z = dinv[n] * (acc + h2s[n]) + b2[0];
        out[n] = 1.0f / (1.0f + expf(-z));
    }
}

extern "C" void kernel_launch(void* const* d_in, const int* in_sizes, int n_in,
                              void* d_out, int out_size, void* d_ws, size_t ws_size,
                              hipStream_t stream) {
    const float* x  = (const float*)d_in[0];
    const int*   ei = (const int*)d_in[1];
    const float* ew = (const float*)d_in[2];
    const float* W1 = (const float*)d_in[3];
    const float* b1 = (const float*)d_in[4];
    const float* W2 = (const float*)d_in[5];
    const float* b2 = (const float*)d_in[6];
    float* out = (float*)d_out;

    const int* src = ei;
    const int* dst = ei + N_EDGES;

    // workspace layout (int2 arrays first for 8B alignment)
    char* ws = (char*)d_ws;
    int2*  edge_b  = (int2*)ws;              ws += (size_t)NBKT * BKT_CAP * sizeof(int2);
    int2*  edge_s  = (int2*)ws;              ws += (size_t)NBKT * BKT_CAP * sizeof(int2);
    int*   gcursor = (int*)ws;               ws += (size_t)NBKT * GC_STRIDE * sizeof(int);
    int*   start_g = (int*)ws;               ws += N_NODES * sizeof(int);
    int*   cnt_g   = (int*)ws;               ws += N_NODES * sizeof(int);
    float* dinv    = (float*)ws;             ws += N_NODES * sizeof(float);
    float* h2s     = (float*)ws;             ws += N_NODES * sizeof(float);
    ws = (char*)(((uintptr_t)ws + 127) & ~(uintptr_t)127);
    __hip_bfloat16* h1b = (__hip_bfloat16*)ws;  // N_NODES * HID_DIM bf16

    hipMemsetAsync(gcursor, 0, NBKT * GC_STRIDE * sizeof(int), stream);
    partgemm_kernel<<<NPASSC + NGEMM, 256, 0, stream>>>(src, dst, ew, gcursor, edge_b, x, W1, h1b);
    bsort_kernel<<<NBKT, 1024, 0, stream>>>(gcursor, edge_b, edge_s, start_g, cnt_g, dinv);
    gather1_layer2_kernel<<<(N_NODES * 64) / 256, 256, 0, stream>>>(start_g, cnt_g, edge_s, h1b, dinv, b1, W2, h2s);
    gather2_final_kernel<<<(N_NODES * 16 + 255) / 256, 256, 0, stream>>>(start_g, cnt_g, edge_s, h2s, dinv, b2, out);
}